// Round 4
// baseline (35546.027 us; speedup 1.0000x reference)
//
#include <hip/hip_runtime.h>
#include <hip/hip_bf16.h>

typedef unsigned int u32;
typedef unsigned short u16;

#define CDIV(a,b) (((a)+(b)-1)/(b))

// ---------- helpers ----------
__device__ __forceinline__ float bf2f(u32 h){ return __uint_as_float(h<<16); }
__device__ __forceinline__ u16 f2bf(float f){
  u32 u=__float_as_uint(f);
  return (u16)((u + 0x7fffu + ((u>>16)&1u))>>16);   // RNE
}
// order-preserving float<->u32 encode for atomic max (init 0 < all finite encodes)
__device__ __forceinline__ u32 fenc(float f){
  u32 u=__float_as_uint(f);
  return (u&0x80000000u)?~u:(u|0x80000000u);
}
__device__ __forceinline__ float fdec2(u32 e){
  u32 u=(e&0x80000000u)?(e&0x7fffffffu):~e;
  return __uint_as_float(u);
}
__device__ __forceinline__ void unpack8(const u16* p, float* xr){
  uint4 v=*(const uint4*)p;
  xr[0]=bf2f(v.x&0xffffu); xr[1]=bf2f(v.x>>16);
  xr[2]=bf2f(v.y&0xffffu); xr[3]=bf2f(v.y>>16);
  xr[4]=bf2f(v.z&0xffffu); xr[5]=bf2f(v.z>>16);
  xr[6]=bf2f(v.w&0xffffu); xr[7]=bf2f(v.w>>16);
}
__device__ __forceinline__ int iclamp(int i, int n){
  unsigned u=(unsigned)i; return (u>=(unsigned)n)?0:i;
}

// ---------- kernels ----------
__global__ void kdiag(float* out, int n, float v){
  int i=blockIdx.x*blockDim.x+threadIdx.x;
  if(i<n) out[i]=(i==0)?v:0.f;
}

__global__ void kzero4(float4* p, long n4){
  long i=(long)blockIdx.x*blockDim.x+threadIdx.x;
  if(i<n4){ float4 z; z.x=z.y=z.z=z.w=0.f; p[i]=z; }
}

// per-(layer,type) bias sum
__global__ void kbsum(const float* __restrict__ gb, float* __restrict__ bsum){
  int l=blockIdx.x/6, t=blockIdx.x%6, j=threadIdx.x;
  const int rd[12]={1,2,3,4,5,2,0,1,2,2,2,2};
  float a=0.f;
  #pragma unroll
  for(int r=0;r<12;++r) if(rd[r]==t) a += gb[(l*12+r)*64 + j];
  bsum[(l*6+t)*64 + j]=a;
}

// embeddings: x[t] = xin @ W + b  -> bf16
template<int D>
__global__ void kemb(const float* __restrict__ xin, const float* __restrict__ W,
                     const float* __restrict__ b, u16* __restrict__ xout, int N){
  int n=blockIdx.x*blockDim.x+threadIdx.x;
  if(n>=N) return;
  float xr[D];
  #pragma unroll
  for(int k=0;k<D;++k) xr[k]=xin[(long)n*D+k];
  u16* orow=xout+(long)n*64;
  for(int j0=0;j0<64;j0+=8){
    float acc[8];
    #pragma unroll
    for(int jj=0;jj<8;++jj){
      float a=b[j0+jj];
      #pragma unroll
      for(int k=0;k<D;++k) a += xr[k]*W[k*64+j0+jj];
      acc[jj]=a;
    }
    uint4 pk;
    pk.x=(u32)f2bf(acc[0])|((u32)f2bf(acc[1])<<16);
    pk.y=(u32)f2bf(acc[2])|((u32)f2bf(acc[3])<<16);
    pk.z=(u32)f2bf(acc[4])|((u32)f2bf(acc[5])<<16);
    pk.w=(u32)f2bf(acc[6])|((u32)f2bf(acc[7])<<16);
    *(uint4*)(orow+j0)=pk;
  }
}

// alpha[n] = x[n] . (W @ a)   (matvec; optional m_enc/s init)
__global__ void kalpha(const u16* __restrict__ x, const float* __restrict__ W,
                       const float* __restrict__ a, float* __restrict__ out,
                       u32* __restrict__ m_enc, float* __restrict__ s, int N){
  __shared__ float wv[64];
  int t=threadIdx.x;
  if(t<64){
    float acc=0.f;
    for(int j=0;j<64;++j) acc += W[t*64+j]*a[j];
    wv[t]=acc;
  }
  __syncthreads();
  int n=blockIdx.x*blockDim.x+t;
  if(n>=N) return;
  const u16* row=x+(long)n*64;
  float acc=0.f;
  #pragma unroll
  for(int j=0;j<64;j+=8){
    float xr[8]; unpack8(row+j,xr);
    #pragma unroll
    for(int k=0;k<8;++k) acc += xr[k]*wv[j+k];
  }
  out[n]=acc;
  if(m_enc){ m_enc[n]=0u; s[n]=0.f; }
}

// per-edge: e = leaky_relu(as[src]+ad[dst]); atomic max into m_enc[dst]
__global__ void kedge_max(const int* __restrict__ src, const int* __restrict__ dst,
                          const float* __restrict__ as_, const float* __restrict__ ad_,
                          float* __restrict__ ep, u32* __restrict__ m_enc, int E, int Ns, int Nd){
  int i=blockIdx.x*blockDim.x+threadIdx.x;
  if(i>=E) return;
  int si=iclamp(src[i],Ns), di=iclamp(dst[i],Nd);
  float e=as_[si]+ad_[di];
  e = e>=0.f ? e : 0.2f*e;
  ep[i]=e;
  atomicMax(m_enc+di, fenc(e));
}

// per-edge: p = exp(e - m[dst]) in place; s[dst] += p
__global__ void kedge_p(const int* __restrict__ dst, float* __restrict__ ep,
                        const u32* __restrict__ m_enc, float* __restrict__ s, int E, int Nd){
  int i=blockIdx.x*blockDim.x+threadIdx.x;
  if(i>=E) return;
  int d=iclamp(dst[i],Nd);
  float p=__expf(ep[i]-fdec2(m_enc[d]));
  ep[i]=p;
  atomicAdd(s+d,p);
}

// Z[d-c0] += (p/s[d]) * x[src]  for edges with dst in [c0,c1)  (16 lanes/edge)
__global__ void kaggrZ(const int* __restrict__ src, const int* __restrict__ dst,
                       const float* __restrict__ p_edge, const float* __restrict__ s,
                       const u16* __restrict__ x, float* __restrict__ Z,
                       int E, int Ns, int c0, int c1){
  long g=(long)blockIdx.x*blockDim.x+threadIdx.x;
  long edge=g>>4; int lane=(int)(g&15);
  if(edge>=E) return;
  int d=dst[edge];
  if(d<c0||d>=c1) return;
  int sr=iclamp(src[edge],Ns);
  float w=p_edge[edge]/(s[d]+1e-16f);
  uint2 v=*(const uint2*)(x+(long)sr*64+lane*4);
  float* zb=Z+((long)(d-c0)*64+lane*4);
  atomicAdd(zb+0, w*bf2f(v.x&0xffffu));
  atomicAdd(zb+1, w*bf2f(v.x>>16));
  atomicAdd(zb+2, w*bf2f(v.y&0xffffu));
  atomicAdd(zb+3, w*bf2f(v.y>>16));
}

// XN[c0+i] += Z[i] @ W   (bf16 read-modify-write, unique writer per node)
__global__ void kgemmZ(const float* __restrict__ Z, const float* __restrict__ W,
                       u32* __restrict__ xn, int c0, int nch){
  int i=blockIdx.x*blockDim.x+threadIdx.x;
  if(i>=nch) return;
  const float* z=Z+(long)i*64;
  float zr[64];
  #pragma unroll
  for(int k=0;k<64;k+=4){
    float4 v=*(const float4*)(z+k);
    zr[k]=v.x; zr[k+1]=v.y; zr[k+2]=v.z; zr[k+3]=v.w;
  }
  u32* xrow=xn+((long)(c0+i)*32);
  for(int j0=0;j0<64;j0+=8){
    float acc[8];
    #pragma unroll
    for(int jj=0;jj<8;++jj){
      float a=0.f;
      #pragma unroll
      for(int k=0;k<64;++k) a += zr[k]*W[k*64+j0+jj];   // wave-uniform W -> scalar loads
      acc[jj]=a;
    }
    uint4 old=*(uint4*)(xrow+(j0>>1));
    uint4 pk;
    pk.x=(u32)f2bf(bf2f(old.x&0xffffu)+acc[0])|((u32)f2bf(bf2f(old.x>>16)+acc[1])<<16);
    pk.y=(u32)f2bf(bf2f(old.y&0xffffu)+acc[2])|((u32)f2bf(bf2f(old.y>>16)+acc[3])<<16);
    pk.z=(u32)f2bf(bf2f(old.z&0xffffu)+acc[4])|((u32)f2bf(bf2f(old.z>>16)+acc[5])<<16);
    pk.w=(u32)f2bf(bf2f(old.w&0xffffu)+acc[6])|((u32)f2bf(bf2f(old.w>>16)+acc[7])<<16);
    *(uint4*)(xrow+(j0>>1))=pk;
  }
}

// x = relu(xn_bf16 + bsum) -> bf16; optionally re-zero xn
__global__ void kreluF(u32* __restrict__ xn, const float* __restrict__ bsum,
                       u16* __restrict__ xo, long n64, int dozero){
  long i=((long)blockIdx.x*blockDim.x+threadIdx.x)*4;   // bf16-element index
  if(i>=n64) return;
  uint2 w=*(uint2*)(xn+(i>>1));
  int j=(int)(i&63);
  float a0=fmaxf(bf2f(w.x&0xffffu)+bsum[j+0],0.f);
  float a1=fmaxf(bf2f(w.x>>16)   +bsum[j+1],0.f);
  float a2=fmaxf(bf2f(w.y&0xffffu)+bsum[j+2],0.f);
  float a3=fmaxf(bf2f(w.y>>16)   +bsum[j+3],0.f);
  uint2 pk;
  pk.x=(u32)f2bf(a0)|((u32)f2bf(a1)<<16);
  pk.y=(u32)f2bf(a2)|((u32)f2bf(a3)<<16);
  *(uint2*)(xo+i)=pk;
  if(dozero){ uint2 z; z.x=0u; z.y=0u; *(uint2*)(xn+(i>>1))=z; }
}

// classifier: out[n] = sigmoid( relu(tx@W1+b1) @ W2 + b2 )
__global__ void kcls(const u16* __restrict__ tx, const float* __restrict__ W1,
                     const float* __restrict__ b1, const float* __restrict__ W2,
                     const float* __restrict__ b2, float* __restrict__ out, int N){
  int n=blockIdx.x*blockDim.x+threadIdx.x;
  if(n>=N) return;
  const u16* row=tx+(long)n*64;
  float xr[64];
  #pragma unroll
  for(int j=0;j<64;j+=8) unpack8(row+j,xr+j);
  float acc2=0.f;
  for(int j=0;j<64;++j){
    float a=b1[j];
    #pragma unroll
    for(int k=0;k<64;++k) a += xr[k]*W1[k*64+j];
    a=fmaxf(a,0.f);
    acc2 += a*W2[j];
  }
  float z=acc2+b2[0];
  out[n]=1.f/(1.f+__expf(-z));
}

__global__ void kpoolzero(float* __restrict__ sum, u32* __restrict__ mx, float* __restrict__ cnt){
  int i=blockIdx.x*blockDim.x+threadIdx.x;
  if(i<1024*64){ sum[i]=0.f; mx[i]=0u; }
  if(i<1024) cnt[i]=0.f;
}

__global__ void kpoolacc(const u16* __restrict__ tx, const int* __restrict__ batch,
                         float* __restrict__ sum, u32* __restrict__ mx,
                         float* __restrict__ cnt, int N){
  long g=(long)blockIdx.x*blockDim.x+threadIdx.x;
  long n=g>>4; int lane=(int)(g&15);
  if(n>=N) return;
  int b=iclamp(batch[n],1024);
  const u16* row=tx+n*64+lane*4;
  uint2 v=*(const uint2*)row;
  float f0=bf2f(v.x&0xffffu), f1=bf2f(v.x>>16), f2=bf2f(v.y&0xffffu), f3=bf2f(v.y>>16);
  float* sb=sum+(long)b*64+lane*4;
  u32*   mb=mx +(long)b*64+lane*4;
  atomicAdd(sb+0,f0); atomicAdd(sb+1,f1); atomicAdd(sb+2,f2); atomicAdd(sb+3,f3);
  atomicMax(mb+0,fenc(f0)); atomicMax(mb+1,fenc(f1)); atomicMax(mb+2,fenc(f2)); atomicMax(mb+3,fenc(f3));
  if(lane==0) atomicAdd(cnt+b,1.f);
}

// pooled = [mean,max] @ pool_W + pool_b ; one block (64 thr) per group
__global__ void kpoolout(const float* __restrict__ sum, const u32* __restrict__ mx,
                         const float* __restrict__ cnt, const float* __restrict__ pW,
                         const float* __restrict__ pb, float* __restrict__ out){
  __shared__ float v[128];
  int g=blockIdx.x, j=threadIdx.x;
  float c=cnt[g];
  float inv=1.f/fmaxf(c,1.f);
  v[j]=sum[(long)g*64+j]*inv;
  v[64+j]=(c>0.f)?fdec2(mx[(long)g*64+j]):0.f;
  __syncthreads();
  float acc=pb[j];
  for(int k=0;k<128;++k) acc += v[k]*pW[k*64+j];
  out[(long)g*64+j]=acc;
}

// ---------- host ----------
extern "C" void kernel_launch(void* const* d_in, const int* in_sizes, int n_in,
                              void* d_out, int out_size, void* d_ws, size_t ws_size,
                              hipStream_t stream){
  const int   NN[6]={100000,150000,500000,20000,5000,50000};
  const long  XO[6]={0,100000,250000,750000,770000,775000};
  const int   RS[12]={0,1,2,2,2,2,1,2,3,4,5,2};
  const int   RD[12]={1,2,3,4,5,2,0,1,2,2,2,2};
  const int   EC[12]={150000,500000,500000,500000,500000,500000,150000,500000,500000,500000,500000,500000};
  const int   CH=167000;   // Z chunk rows (f32): 42.75 MB; 500k dst -> 3 passes

  const float* xin[6];  for(int t=0;t<6;++t) xin[t]=(const float*)d_in[t];
  const float* embW[6]; const float* embB[6];
  for(int t=0;t<6;++t){ embW[t]=(const float*)d_in[6+2*t]; embB[t]=(const float*)d_in[7+2*t]; }
  const float* gatW =(const float*)d_in[18];
  const float* gatAs=(const float*)d_in[19];
  const float* gatAd=(const float*)d_in[20];
  const float* gatB =(const float*)d_in[21];
  const float* poolW=(const float*)d_in[22];
  const float* poolB=(const float*)d_in[23];
  const float* W1=(const float*)d_in[24];
  const float* b1=(const float*)d_in[25];
  const float* W2=(const float*)d_in[26];
  const float* b2=(const float*)d_in[27];
  const int* esrc[12]; const int* edst[12];
  for(int r=0;r<12;++r){ esrc[r]=(const int*)d_in[28+2*r]; edst[r]=(const int*)d_in[29+2*r]; }
  const int* batch=(const int*)d_in[52];
  float* out=(float*)d_out;
  (void)in_sizes; (void)n_in;

  // ---- cursor-based workspace layout, 256B aligned (~264.5 MB total) ----
  char* w=(char*)d_ws;
  size_t off=0;
  auto take=[&](size_t bytes)->void*{
    void* p=w+off; off+=(bytes+(size_t)255)&~(size_t)255; return p;
  };
  u16*   X    =(u16*)  take(105600000);        // 825000*64 bf16 (current features)
  u32*   XN   =(u32*)  take(105600000);        // 825000*64 bf16 (next-layer accum, u32 view)
  float* Z    =(float*)take((size_t)CH*64*4);  // per-relation raw-feature aggregation, f32
  float* ASRC =(float*)take(2000000);
  float* ADST =(float*)take(2000000);
  u32*   MENC =(u32*)  take(2000000);
  float* SDEN =(float*)take(2000000);
  float* EP   =(float*)take(2000000);
  float* BSUM =(float*)take(4608);
  float* PSUM =(float*)take(262144);
  u32*   PMAX =(u32*)  take(262144);
  float* PCNT =(float*)take(4096);
  size_t need=off;

  const int B=256;

  if(ws_size<need){
    kdiag<<<CDIV(out_size,B),B,0,stream>>>(out,out_size,(float)(ws_size>>20));
    return;
  }

  // zero XN (bf16 accum) for layer 0; bias sums
  kzero4<<<CDIV(6600000L,(long)B),B,0,stream>>>((float4*)XN,6600000L);
  kbsum<<<18,64,0,stream>>>(gatB,BSUM);

  // embeddings
  kemb< 8><<<CDIV(NN[0],B),B,0,stream>>>(xin[0],embW[0],embB[0],X+XO[0]*64,NN[0]);
  kemb< 6><<<CDIV(NN[1],B),B,0,stream>>>(xin[1],embW[1],embB[1],X+XO[1]*64,NN[1]);
  kemb<12><<<CDIV(NN[2],B),B,0,stream>>>(xin[2],embW[2],embB[2],X+XO[2]*64,NN[2]);
  kemb< 6><<<CDIV(NN[3],B),B,0,stream>>>(xin[3],embW[3],embB[3],X+XO[3]*64,NN[3]);
  kemb< 5><<<CDIV(NN[4],B),B,0,stream>>>(xin[4],embW[4],embB[4],X+XO[4]*64,NN[4]);
  kemb< 5><<<CDIV(NN[5],B),B,0,stream>>>(xin[5],embW[5],embB[5],X+XO[5]*64,NN[5]);

  for(int l=0;l<3;++l){
    for(int r=0;r<12;++r){
      int st=RS[r], dt=RD[r];
      const float* Wlr=gatW+(long)(l*12+r)*4096;
      const float* aslr=gatAs+(long)(l*12+r)*64;
      const float* adlr=gatAd+(long)(l*12+r)*64;
      // attention scalars (matvec trick: x.(W@a)), softmax max+denom
      kalpha<<<CDIV(NN[dt],B),B,0,stream>>>(X+XO[dt]*64,Wlr,adlr,ADST,MENC,SDEN,NN[dt]);
      kalpha<<<CDIV(NN[st],B),B,0,stream>>>(X+XO[st]*64,Wlr,aslr,ASRC,nullptr,nullptr,NN[st]);
      kedge_max<<<CDIV(EC[r],B),B,0,stream>>>(esrc[r],edst[r],ASRC,ADST,EP,MENC,EC[r],NN[st],NN[dt]);
      kedge_p<<<CDIV(EC[r],B),B,0,stream>>>(edst[r],EP,MENC,SDEN,EC[r],NN[dt]);
      // chunked raw-feature aggregation + GEMM into XN
      for(int c0=0;c0<NN[dt];c0+=CH){
        int c1=min(c0+CH,NN[dt]);
        long z4=(long)(c1-c0)*16;
        kzero4<<<CDIV(z4,(long)B),B,0,stream>>>((float4*)Z,z4);
        kaggrZ<<<CDIV((long)EC[r]*16,(long)B),B,0,stream>>>(esrc[r],edst[r],EP,SDEN,
                                                            X+XO[st]*64,Z,EC[r],NN[st],c0,c1);
        kgemmZ<<<CDIV(c1-c0,B),B,0,stream>>>(Z,Wlr,XN+XO[dt]*32,c0,c1-c0);
      }
    }
    for(int t=0;t<6;++t){
      long n64=(long)NN[t]*64;
      kreluF<<<CDIV(n64/4,(long)B),B,0,stream>>>(XN+XO[t]*32,BSUM+(l*6+t)*64,X+XO[t]*64,n64,(l<2)?1:0);
    }
  }

  // classifier on transactions
  kcls<<<CDIV(NN[2],B),B,0,stream>>>(X+XO[2]*64,W1,b1,W2,b2,out,NN[2]);

  // pooling
  kpoolzero<<<CDIV(65536,B),B,0,stream>>>(PSUM,PMAX,PCNT);
  kpoolacc<<<CDIV((long)NN[2]*16,(long)B),B,0,stream>>>(X+XO[2]*64,batch,PSUM,PMAX,PCNT,NN[2]);
  kpoolout<<<1024,64,0,stream>>>(PSUM,PMAX,PCNT,poolW,poolB,out+500000);
}

// Round 5
// 7727.749 us; speedup vs baseline: 4.5998x; 4.5998x over previous
//
#include <hip/hip_runtime.h>
#include <hip/hip_bf16.h>

typedef unsigned int u32;
typedef unsigned short u16;

#define CDIV(a,b) (((a)+(b)-1)/(b))

// ---------- helpers ----------
__device__ __forceinline__ float bf2f(u32 h){ return __uint_as_float(h<<16); }
__device__ __forceinline__ u16 f2bf(float f){
  u32 u=__float_as_uint(f);
  return (u16)((u + 0x7fffu + ((u>>16)&1u))>>16);   // RNE
}
__device__ __forceinline__ u32 fenc(float f){
  u32 u=__float_as_uint(f);
  return (u&0x80000000u)?~u:(u|0x80000000u);
}
__device__ __forceinline__ float fdec2(u32 e){
  u32 u=(e&0x80000000u)?(e&0x7fffffffu):~e;
  return __uint_as_float(u);
}
__device__ __forceinline__ void unpack8(const u16* p, float* xr){
  uint4 v=*(const uint4*)p;
  xr[0]=bf2f(v.x&0xffffu); xr[1]=bf2f(v.x>>16);
  xr[2]=bf2f(v.y&0xffffu); xr[3]=bf2f(v.y>>16);
  xr[4]=bf2f(v.z&0xffffu); xr[5]=bf2f(v.z>>16);
  xr[6]=bf2f(v.w&0xffffu); xr[7]=bf2f(v.w>>16);
}
__device__ __forceinline__ int iclamp(int i, int n){
  unsigned u=(unsigned)i; return (u>=(unsigned)n)?0:i;
}

// ---------- misc kernels ----------
__global__ void kdiag(float* out, int n, float v){
  int i=blockIdx.x*blockDim.x+threadIdx.x;
  if(i<n) out[i]=(i==0)?v:0.f;
}
__global__ void kzero4(float4* p, long n4){
  long i=(long)blockIdx.x*blockDim.x+threadIdx.x;
  if(i<n4){ float4 z; z.x=z.y=z.z=z.w=0.f; p[i]=z; }
}
__global__ void kzeroi(int* p, int n){
  int i=blockIdx.x*blockDim.x+threadIdx.x;
  if(i<n) p[i]=0;
}
__global__ void kbsum(const float* __restrict__ gb, float* __restrict__ bsum){
  int l=blockIdx.x/6, t=blockIdx.x%6, j=threadIdx.x;
  const int rd[12]={1,2,3,4,5,2,0,1,2,2,2,2};
  float a=0.f;
  #pragma unroll
  for(int r=0;r<12;++r) if(rd[r]==t) a += gb[(l*12+r)*64 + j];
  bsum[(l*6+t)*64 + j]=a;
}

// ---------- CSR build ----------
__global__ void khist(const int* __restrict__ dst, int* __restrict__ hist, int E, int Nd){
  int i=blockIdx.x*blockDim.x+threadIdx.x;
  if(i>=E) return;
  atomicAdd(hist+iclamp(dst[i],Nd),1);
}
// block scans 4096 elems (256 thr x 16); rp gets within-block exclusive scan; bsum[b]=block total
__global__ void kscan1(const int* __restrict__ hist, int* __restrict__ rp, int* __restrict__ bsum, int Nd){
  __shared__ int lds[256];
  __shared__ int pref[256];
  int b=blockIdx.x, t=threadIdx.x;
  int base=b*4096+t*16;
  int v[16]; int s=0;
  #pragma unroll
  for(int k=0;k<16;++k){ int idx=base+k; v[k]=(idx<Nd)?hist[idx]:0; s+=v[k]; }
  lds[t]=s; __syncthreads();
  if(t==0){ int run=0; for(int i=0;i<256;++i){ pref[i]=run; run+=lds[i]; } bsum[b]=run; }
  __syncthreads();
  int run=pref[t];
  #pragma unroll
  for(int k=0;k<16;++k){ int idx=base+k; if(idx<Nd) rp[idx]=run; run+=v[k]; }
}
__global__ void kscan2(int* bsum, int nb){
  if(blockIdx.x==0&&threadIdx.x==0){
    int run=0;
    for(int i=0;i<nb;++i){ int x=bsum[i]; bsum[i]=run; run+=x; }
    bsum[nb]=run;
  }
}
__global__ void kscan3(int* __restrict__ rp, const int* __restrict__ bsum, int Nd, int nb){
  int i=blockIdx.x*blockDim.x+threadIdx.x;
  if(i<Nd) rp[i]+=bsum[i>>12];
  if(i==0) rp[Nd]=bsum[nb];
}
__global__ void kcopyi(const int* __restrict__ a, int* __restrict__ b, int n){
  int i=blockIdx.x*blockDim.x+threadIdx.x;
  if(i<n) b[i]=a[i];
}
__global__ void kscatter(const int* __restrict__ src, const int* __restrict__ dst,
                         int* __restrict__ cur, int* __restrict__ srcs, int E, int Ns, int Nd){
  int i=blockIdx.x*blockDim.x+threadIdx.x;
  if(i>=E) return;
  int d=iclamp(dst[i],Nd);
  int pos=atomicAdd(cur+d,1);
  srcs[pos]=iclamp(src[i],Ns);
}

// ---------- embeddings ----------
template<int D>
__global__ void kemb(const float* __restrict__ xin, const float* __restrict__ W,
                     const float* __restrict__ b, u16* __restrict__ xout, int N){
  int n=blockIdx.x*blockDim.x+threadIdx.x;
  if(n>=N) return;
  float xr[D];
  #pragma unroll
  for(int k=0;k<D;++k) xr[k]=xin[(long)n*D+k];
  u16* orow=xout+(long)n*64;
  for(int j0=0;j0<64;j0+=8){
    float acc[8];
    #pragma unroll
    for(int jj=0;jj<8;++jj){
      float a=b[j0+jj];
      #pragma unroll
      for(int k=0;k<D;++k) a += xr[k]*W[k*64+j0+jj];
      acc[jj]=a;
    }
    uint4 pk;
    pk.x=(u32)f2bf(acc[0])|((u32)f2bf(acc[1])<<16);
    pk.y=(u32)f2bf(acc[2])|((u32)f2bf(acc[3])<<16);
    pk.z=(u32)f2bf(acc[4])|((u32)f2bf(acc[5])<<16);
    pk.w=(u32)f2bf(acc[6])|((u32)f2bf(acc[7])<<16);
    *(uint4*)(orow+j0)=pk;
  }
}

// alpha[n] = x[n] . (W @ a)
__global__ void kalpha(const u16* __restrict__ x, const float* __restrict__ W,
                       const float* __restrict__ a, float* __restrict__ out, int N){
  __shared__ float wv[64];
  int t=threadIdx.x;
  if(t<64){
    float acc=0.f;
    for(int j=0;j<64;++j) acc += W[t*64+j]*a[j];
    wv[t]=acc;
  }
  __syncthreads();
  int n=blockIdx.x*blockDim.x+t;
  if(n>=N) return;
  const u16* row=x+(long)n*64;
  float acc=0.f;
  #pragma unroll
  for(int j=0;j<64;j+=8){
    float xr[8]; unpack8(row+j,xr);
    #pragma unroll
    for(int k=0;k<8;++k) acc += xr[k]*wv[j+k];
  }
  out[n]=acc;
}

// ---------- fused per-dst-node GAT: softmax + aggregate + GEMM + XN accumulate ----------
__global__ void kfused(const int* __restrict__ rowptr, const int* __restrict__ srcs,
                       const float* __restrict__ as_, const float* __restrict__ ad_,
                       const u16* __restrict__ x, const float* __restrict__ W,
                       u32* __restrict__ xn, int Nd){
  int d=blockIdx.x*blockDim.x+threadIdx.x;
  if(d>=Nd) return;
  int b0=rowptr[d], b1=rowptr[d+1];
  if(b0==b1) return;                        // no in-edges: contribution is exactly 0
  float adv=ad_[d];
  // pass A: max of leaky_relu scores
  float m=-3.4e38f;
  for(int e=b0;e<b1;++e){
    float ev=as_[srcs[e]]+adv;
    ev = ev>=0.f ? ev : 0.2f*ev;
    m=fmaxf(m,ev);
  }
  // pass B: p=exp(e-m); s += p; z += p*x[src]
  float s=0.f;
  float z[64];
  #pragma unroll
  for(int k=0;k<64;++k) z[k]=0.f;
  for(int e=b0;e<b1;++e){
    int sr=srcs[e];
    float ev=as_[sr]+adv;
    ev = ev>=0.f ? ev : 0.2f*ev;
    float p=__expf(ev-m);
    s+=p;
    const u16* row=x+(long)sr*64;
    #pragma unroll
    for(int j=0;j<64;j+=8){
      float xr[8]; unpack8(row+j,xr);
      #pragma unroll
      for(int k=0;k<8;++k) z[j+k]+=p*xr[k];
    }
  }
  float inv=1.f/(s+1e-16f);
  #pragma unroll
  for(int k=0;k<64;++k) z[k]*=inv;
  // GEMM row: out[j] = sum_k z[k]*W[k*64+j]; RMW bf16 into xn
  u32* xrow=xn+(long)d*32;
  for(int j0=0;j0<64;j0+=8){
    float acc[8];
    #pragma unroll
    for(int jj=0;jj<8;++jj) acc[jj]=0.f;
    #pragma unroll
    for(int k=0;k<64;++k){
      const float4* W4=(const float4*)(W+k*64+j0);
      float4 wa=W4[0], wb=W4[1];
      float zk=z[k];
      acc[0]+=zk*wa.x; acc[1]+=zk*wa.y; acc[2]+=zk*wa.z; acc[3]+=zk*wa.w;
      acc[4]+=zk*wb.x; acc[5]+=zk*wb.y; acc[6]+=zk*wb.z; acc[7]+=zk*wb.w;
    }
    uint4 old=*(uint4*)(xrow+(j0>>1));
    uint4 pk;
    pk.x=(u32)f2bf(bf2f(old.x&0xffffu)+acc[0])|((u32)f2bf(bf2f(old.x>>16)+acc[1])<<16);
    pk.y=(u32)f2bf(bf2f(old.y&0xffffu)+acc[2])|((u32)f2bf(bf2f(old.y>>16)+acc[3])<<16);
    pk.z=(u32)f2bf(bf2f(old.z&0xffffu)+acc[4])|((u32)f2bf(bf2f(old.z>>16)+acc[5])<<16);
    pk.w=(u32)f2bf(bf2f(old.w&0xffffu)+acc[6])|((u32)f2bf(bf2f(old.w>>16)+acc[7])<<16);
    *(uint4*)(xrow+(j0>>1))=pk;
  }
}

// x = relu(xn_bf16 + bsum) -> bf16; optionally re-zero xn
__global__ void kreluF(u32* __restrict__ xn, const float* __restrict__ bsum,
                       u16* __restrict__ xo, long n64, int dozero){
  long i=((long)blockIdx.x*blockDim.x+threadIdx.x)*4;
  if(i>=n64) return;
  uint2 w=*(uint2*)(xn+(i>>1));
  int j=(int)(i&63);
  float a0=fmaxf(bf2f(w.x&0xffffu)+bsum[j+0],0.f);
  float a1=fmaxf(bf2f(w.x>>16)   +bsum[j+1],0.f);
  float a2=fmaxf(bf2f(w.y&0xffffu)+bsum[j+2],0.f);
  float a3=fmaxf(bf2f(w.y>>16)   +bsum[j+3],0.f);
  uint2 pk;
  pk.x=(u32)f2bf(a0)|((u32)f2bf(a1)<<16);
  pk.y=(u32)f2bf(a2)|((u32)f2bf(a3)<<16);
  *(uint2*)(xo+i)=pk;
  if(dozero){ uint2 z; z.x=0u; z.y=0u; *(uint2*)(xn+(i>>1))=z; }
}

// classifier
__global__ void kcls(const u16* __restrict__ tx, const float* __restrict__ W1,
                     const float* __restrict__ b1, const float* __restrict__ W2,
                     const float* __restrict__ b2, float* __restrict__ out, int N){
  int n=blockIdx.x*blockDim.x+threadIdx.x;
  if(n>=N) return;
  const u16* row=tx+(long)n*64;
  float xr[64];
  #pragma unroll
  for(int j=0;j<64;j+=8) unpack8(row+j,xr+j);
  float acc2=0.f;
  for(int j=0;j<64;++j){
    float a=b1[j];
    #pragma unroll
    for(int k=0;k<64;++k) a += xr[k]*W1[k*64+j];
    a=fmaxf(a,0.f);
    acc2 += a*W2[j];
  }
  float zv=acc2+b2[0];
  out[n]=1.f/(1.f+__expf(-zv));
}

__global__ void kpoolzero(float* __restrict__ sum, u32* __restrict__ mx, float* __restrict__ cnt){
  int i=blockIdx.x*blockDim.x+threadIdx.x;
  if(i<1024*64){ sum[i]=0.f; mx[i]=0u; }
  if(i<1024) cnt[i]=0.f;
}
__global__ void kpoolacc(const u16* __restrict__ tx, const int* __restrict__ batch,
                         float* __restrict__ sum, u32* __restrict__ mx,
                         float* __restrict__ cnt, int N){
  long g=(long)blockIdx.x*blockDim.x+threadIdx.x;
  long n=g>>4; int lane=(int)(g&15);
  if(n>=N) return;
  int b=iclamp(batch[n],1024);
  const u16* row=tx+n*64+lane*4;
  uint2 v=*(const uint2*)row;
  float f0=bf2f(v.x&0xffffu), f1=bf2f(v.x>>16), f2=bf2f(v.y&0xffffu), f3=bf2f(v.y>>16);
  float* sb=sum+(long)b*64+lane*4;
  u32*   mb=mx +(long)b*64+lane*4;
  atomicAdd(sb+0,f0); atomicAdd(sb+1,f1); atomicAdd(sb+2,f2); atomicAdd(sb+3,f3);
  atomicMax(mb+0,fenc(f0)); atomicMax(mb+1,fenc(f1)); atomicMax(mb+2,fenc(f2)); atomicMax(mb+3,fenc(f3));
  if(lane==0) atomicAdd(cnt+b,1.f);
}
__global__ void kpoolout(const float* __restrict__ sum, const u32* __restrict__ mx,
                         const float* __restrict__ cnt, const float* __restrict__ pW,
                         const float* __restrict__ pb, float* __restrict__ out){
  __shared__ float v[128];
  int g=blockIdx.x, j=threadIdx.x;
  float c=cnt[g];
  float inv=1.f/fmaxf(c,1.f);
  v[j]=sum[(long)g*64+j]*inv;
  v[64+j]=(c>0.f)?fdec2(mx[(long)g*64+j]):0.f;
  __syncthreads();
  float acc=pb[j];
  for(int k=0;k<128;++k) acc += v[k]*pW[k*64+j];
  out[(long)g*64+j]=acc;
}

// ---------- host ----------
extern "C" void kernel_launch(void* const* d_in, const int* in_sizes, int n_in,
                              void* d_out, int out_size, void* d_ws, size_t ws_size,
                              hipStream_t stream){
  const int   NN[6]={100000,150000,500000,20000,5000,50000};
  const long  XO[6]={0,100000,250000,750000,770000,775000};
  const int   RS[12]={0,1,2,2,2,2,1,2,3,4,5,2};
  const int   RD[12]={1,2,3,4,5,2,0,1,2,2,2,2};
  const int   EC[12]={150000,500000,500000,500000,500000,500000,150000,500000,500000,500000,500000,500000};

  const float* xin[6];  for(int t=0;t<6;++t) xin[t]=(const float*)d_in[t];
  const float* embW[6]; const float* embB[6];
  for(int t=0;t<6;++t){ embW[t]=(const float*)d_in[6+2*t]; embB[t]=(const float*)d_in[7+2*t]; }
  const float* gatW =(const float*)d_in[18];
  const float* gatAs=(const float*)d_in[19];
  const float* gatAd=(const float*)d_in[20];
  const float* gatB =(const float*)d_in[21];
  const float* poolW=(const float*)d_in[22];
  const float* poolB=(const float*)d_in[23];
  const float* W1=(const float*)d_in[24];
  const float* b1=(const float*)d_in[25];
  const float* W2=(const float*)d_in[26];
  const float* b2=(const float*)d_in[27];
  const int* esrc[12]; const int* edst[12];
  for(int r=0;r<12;++r){ esrc[r]=(const int*)d_in[28+2*r]; edst[r]=(const int*)d_in[29+2*r]; }
  const int* batch=(const int*)d_in[52];
  float* out=(float*)d_out;
  (void)in_sizes; (void)n_in;

  // CSR layout offsets (host-side constants)
  long RPoff[13]; RPoff[0]=0;
  long SEoff[13]; SEoff[0]=0;
  for(int r=0;r<12;++r){ RPoff[r+1]=RPoff[r]+NN[RD[r]]+1; SEoff[r+1]=SEoff[r]+EC[r]; }
  // RPoff[12]=3,475,012 ints; SEoff[12]=5,300,000 ints

  // ---- workspace layout (~253 MB) ----
  char* w=(char*)d_ws;
  size_t off=0;
  auto take=[&](size_t bytes)->void*{
    void* p=w+off; off+=(bytes+(size_t)255)&~(size_t)255; return p;
  };
  u16*   X    =(u16*)  take(105600000);           // 825000*64 bf16
  u32*   XN   =(u32*)  take(105600000);           // 825000*64 bf16 accum (u32 view)
  int*   RP   =(int*)  take((size_t)RPoff[12]*4); // CSR rowptrs, all relations
  int*   SRCS =(int*)  take((size_t)SEoff[12]*4); // CSR sorted src ids
  int*   CUR  =(int*)  take(2000008);             // scatter cursors (max Nd+1)
  int*   BS   =(int*)  take(1024);                // scan block sums (<=256)
  float* ASRC =(float*)take(2000000);
  float* ADST =(float*)take(2000000);
  float* BSUM =(float*)take(4608);
  float* PSUM =(float*)take(262144);
  u32*   PMAX =(u32*)  take(262144);
  float* PCNT =(float*)take(4096);
  size_t need=off;

  const int B=256;

  if(ws_size<need){
    kdiag<<<CDIV(out_size,B),B,0,stream>>>(out,out_size,(float)(ws_size>>20));
    return;
  }

  // ---- CSR build (once; reused across the 3 layers) ----
  for(int r=0;r<12;++r){
    int Nd=NN[RD[r]], Ns=NN[RS[r]], E=EC[r];
    int* rp=RP+RPoff[r];
    int* srcs=SRCS+SEoff[r];
    int nb=CDIV(Nd,4096);
    kzeroi<<<CDIV(Nd,B),B,0,stream>>>(CUR,Nd);                 // CUR as histogram scratch
    khist<<<CDIV(E,B),B,0,stream>>>(edst[r],CUR,E,Nd);
    kscan1<<<nb,256,0,stream>>>(CUR,rp,BS,Nd);
    kscan2<<<1,64,0,stream>>>(BS,nb);
    kscan3<<<CDIV(Nd,B),B,0,stream>>>(rp,BS,Nd,nb);
    kcopyi<<<CDIV(Nd,B),B,0,stream>>>(rp,CUR,Nd);
    kscatter<<<CDIV(E,B),B,0,stream>>>(esrc[r],edst[r],CUR,srcs,E,Ns,Nd);
  }

  // zero XN accum; bias sums
  kzero4<<<CDIV(6600000L,(long)B),B,0,stream>>>((float4*)XN,6600000L);
  kbsum<<<18,64,0,stream>>>(gatB,BSUM);

  // embeddings
  kemb< 8><<<CDIV(NN[0],B),B,0,stream>>>(xin[0],embW[0],embB[0],X+XO[0]*64,NN[0]);
  kemb< 6><<<CDIV(NN[1],B),B,0,stream>>>(xin[1],embW[1],embB[1],X+XO[1]*64,NN[1]);
  kemb<12><<<CDIV(NN[2],B),B,0,stream>>>(xin[2],embW[2],embB[2],X+XO[2]*64,NN[2]);
  kemb< 6><<<CDIV(NN[3],B),B,0,stream>>>(xin[3],embW[3],embB[3],X+XO[3]*64,NN[3]);
  kemb< 5><<<CDIV(NN[4],B),B,0,stream>>>(xin[4],embW[4],embB[4],X+XO[4]*64,NN[4]);
  kemb< 5><<<CDIV(NN[5],B),B,0,stream>>>(xin[5],embW[5],embB[5],X+XO[5]*64,NN[5]);

  for(int l=0;l<3;++l){
    for(int r=0;r<12;++r){
      int st=RS[r], dt=RD[r];
      const float* Wlr=gatW+(long)(l*12+r)*4096;
      const float* aslr=gatAs+(long)(l*12+r)*64;
      const float* adlr=gatAd+(long)(l*12+r)*64;
      kalpha<<<CDIV(NN[st],B),B,0,stream>>>(X+XO[st]*64,Wlr,aslr,ASRC,NN[st]);
      kalpha<<<CDIV(NN[dt],B),B,0,stream>>>(X+XO[dt]*64,Wlr,adlr,ADST,NN[dt]);
      kfused<<<CDIV(NN[dt],B),B,0,stream>>>(RP+RPoff[r],SRCS+SEoff[r],ASRC,ADST,
                                            X+XO[st]*64,Wlr,XN+XO[dt]*32,NN[dt]);
    }
    for(int t=0;t<6;++t){
      long n64=(long)NN[t]*64;
      kreluF<<<CDIV(n64/4,(long)B),B,0,stream>>>(XN+XO[t]*32,BSUM+(l*6+t)*64,X+XO[t]*64,n64,(l<2)?1:0);
    }
  }

  // classifier on transactions
  kcls<<<CDIV(NN[2],B),B,0,stream>>>(X+XO[2]*64,W1,b1,W2,b2,out,NN[2]);

  // pooling
  kpoolzero<<<CDIV(65536,B),B,0,stream>>>(PSUM,PMAX,PCNT);
  kpoolacc<<<CDIV((long)NN[2]*16,(long)B),B,0,stream>>>(X+XO[2]*64,batch,PSUM,PMAX,PCNT,NN[2]);
  kpoolout<<<1024,64,0,stream>>>(PSUM,PMAX,PCNT,poolW,poolB,out+500000);
}

// Round 6
// 6042.008 us; speedup vs baseline: 5.8831x; 1.2790x over previous
//
#include <hip/hip_runtime.h>
#include <hip/hip_bf16.h>

typedef unsigned int u32;
typedef unsigned short u16;

#define CDIV(a,b) (((a)+(b)-1)/(b))

// ---------- helpers ----------
__device__ __forceinline__ float bf2f(u32 h){ return __uint_as_float(h<<16); }
__device__ __forceinline__ u16 f2bf(float f){
  u32 u=__float_as_uint(f);
  return (u16)((u + 0x7fffu + ((u>>16)&1u))>>16);   // RNE
}
__device__ __forceinline__ void unpack8(const u16* p, float* xr){
  uint4 v=*(const uint4*)p;
  xr[0]=bf2f(v.x&0xffffu); xr[1]=bf2f(v.x>>16);
  xr[2]=bf2f(v.y&0xffffu); xr[3]=bf2f(v.y>>16);
  xr[4]=bf2f(v.z&0xffffu); xr[5]=bf2f(v.z>>16);
  xr[6]=bf2f(v.w&0xffffu); xr[7]=bf2f(v.w>>16);
}
__device__ __forceinline__ int iclamp(int i, int n){
  unsigned u=(unsigned)i; return (u>=(unsigned)n)?0:i;
}

struct EdgeTab {
  const int* dst[12];
  const int* src[12];
  int seo[13];   // edge-concat offsets
  int rpo[13];   // rowptr-concat offsets
  int nd[12];
  int ns[12];
};

// ---------- misc ----------
__global__ void kdiag(float* out, int n, float v){
  int i=blockIdx.x*blockDim.x+threadIdx.x;
  if(i<n) out[i]=(i==0)?v:0.f;
}
__global__ void kzero4(float4* p, long n4){
  long i=(long)blockIdx.x*blockDim.x+threadIdx.x;
  if(i<n4){ float4 z; z.x=z.y=z.z=z.w=0.f; p[i]=z; }
}
__global__ void kzeroi(int* p, int n){
  int i=blockIdx.x*blockDim.x+threadIdx.x;
  if(i<n) p[i]=0;
}
__global__ void kbsum(const float* __restrict__ gb, float* __restrict__ bsum){
  int l=blockIdx.x/6, t=blockIdx.x%6, j=threadIdx.x;
  const int rd[12]={1,2,3,4,5,2,0,1,2,2,2,2};
  float a=0.f;
  #pragma unroll
  for(int r=0;r<12;++r) if(rd[r]==t) a += gb[(l*12+r)*64 + j];
  bsum[(l*6+t)*64 + j]=a;
}

// ---------- CSR build (concatenated, 6 dispatches total) ----------
__global__ void khistAll(EdgeTab et, int* __restrict__ RP, int Etot){
  int i=blockIdx.x*blockDim.x+threadIdx.x;
  if(i>=Etot) return;
  int r=0;
  #pragma unroll
  for(int k=1;k<12;++k) r += (i>=et.seo[k]) ? 1 : 0;
  int e=i-et.seo[r];
  int d=iclamp(et.dst[r][e], et.nd[r]);
  atomicAdd(RP+et.rpo[r]+d,1);
}
// block scans 4096 elems; rp <- within-block exclusive scan of hist(in place ok via sep ptr); bsum[b]=total
__global__ void kscan1(const int* __restrict__ hist, int* __restrict__ rp, int* __restrict__ bsum, int N){
  __shared__ int lds[256];
  __shared__ int pref[256];
  int b=blockIdx.x, t=threadIdx.x;
  int base=b*4096+t*16;
  int v[16]; int s=0;
  #pragma unroll
  for(int k=0;k<16;++k){ int idx=base+k; v[k]=(idx<N)?hist[idx]:0; s+=v[k]; }
  lds[t]=s; __syncthreads();
  if(t==0){ int run=0; for(int i=0;i<256;++i){ pref[i]=run; run+=lds[i]; } bsum[b]=run; }
  __syncthreads();
  int run=pref[t];
  #pragma unroll
  for(int k=0;k<16;++k){ int idx=base+k; if(idx<N) rp[idx]=run; run+=v[k]; }
}
__global__ void kscan2b(int* bsum, int nb){
  __shared__ int lds[256], pref[256], tot;
  int t=threadIdx.x;
  int v[4]; int s=0;
  #pragma unroll
  for(int k=0;k<4;++k){ int idx=t*4+k; v[k]=(idx<nb)?bsum[idx]:0; s+=v[k]; }
  lds[t]=s; __syncthreads();
  if(t==0){ int run=0; for(int i=0;i<256;++i){ pref[i]=run; run+=lds[i]; } tot=run; }
  __syncthreads();
  int run=pref[t];
  #pragma unroll
  for(int k=0;k<4;++k){ int idx=t*4+k; if(idx<nb){ int x=v[k]; bsum[idx]=run; run+=x; } }
  if(t==0) bsum[nb]=tot;
}
__global__ void kscan3(int* __restrict__ rp, const int* __restrict__ bsum, int N){
  int i=blockIdx.x*blockDim.x+threadIdx.x;
  if(i<N) rp[i]+=bsum[i>>12];
}
// scatter, using RP itself as cursors (after: rp[d] = END of row d)
__global__ void kscatterAll(EdgeTab et, int* __restrict__ RP, int* __restrict__ SRCS, int Etot){
  int i=blockIdx.x*blockDim.x+threadIdx.x;
  if(i>=Etot) return;
  int r=0;
  #pragma unroll
  for(int k=1;k<12;++k) r += (i>=et.seo[k]) ? 1 : 0;
  int e=i-et.seo[r];
  int d=iclamp(et.dst[r][e], et.nd[r]);
  int pos=atomicAdd(RP+et.rpo[r]+d,1);
  SRCS[pos]=iclamp(et.src[r][e], et.ns[r]);
}

// ---------- embeddings ----------
template<int D>
__global__ void kemb(const float* __restrict__ xin, const float* __restrict__ W,
                     const float* __restrict__ b, u16* __restrict__ xout, int N){
  int n=blockIdx.x*blockDim.x+threadIdx.x;
  if(n>=N) return;
  float xr[D];
  #pragma unroll
  for(int k=0;k<D;++k) xr[k]=xin[(long)n*D+k];
  u16* orow=xout+(long)n*64;
  for(int j0=0;j0<64;j0+=8){
    float acc[8];
    #pragma unroll
    for(int jj=0;jj<8;++jj){
      float a=b[j0+jj];
      #pragma unroll
      for(int k=0;k<D;++k) a += xr[k]*W[k*64+j0+jj];
      acc[jj]=a;
    }
    uint4 pk;
    pk.x=(u32)f2bf(acc[0])|((u32)f2bf(acc[1])<<16);
    pk.y=(u32)f2bf(acc[2])|((u32)f2bf(acc[3])<<16);
    pk.z=(u32)f2bf(acc[4])|((u32)f2bf(acc[5])<<16);
    pk.w=(u32)f2bf(acc[6])|((u32)f2bf(acc[7])<<16);
    *(uint4*)(orow+j0)=pk;
  }
}

// fused src+dst alpha: oas[n]=x_src[n].(W@a_s), oad[n]=x_dst[n].(W@a_d)
__global__ void kalphaF(const u16* __restrict__ xs_, const u16* __restrict__ xd_,
                        const float* __restrict__ W,
                        const float* __restrict__ av_s, const float* __restrict__ av_d,
                        float* __restrict__ oas, float* __restrict__ oad, int Ns, int Nd){
  __shared__ float wvs[64], wvd[64];
  int t=threadIdx.x;
  if(t<64){
    float a=0.f,b=0.f;
    for(int j=0;j<64;++j){ float wv=W[t*64+j]; a+=wv*av_s[j]; b+=wv*av_d[j]; }
    wvs[t]=a; wvd[t]=b;
  }
  __syncthreads();
  int n=blockIdx.x*blockDim.x+t;
  if(n<Ns){
    const u16* row=xs_+(long)n*64;
    float acc=0.f;
    #pragma unroll
    for(int j=0;j<64;j+=8){
      float xr[8]; unpack8(row+j,xr);
      #pragma unroll
      for(int k=0;k<8;++k) acc += xr[k]*wvs[j+k];
    }
    oas[n]=acc;
  } else if(n<Ns+Nd){
    int m=n-Ns;
    const u16* row=xd_+(long)m*64;
    float acc=0.f;
    #pragma unroll
    for(int j=0;j<64;j+=8){
      float xr[8]; unpack8(row+j,xr);
      #pragma unroll
      for(int k=0;k<8;++k) acc += xr[k]*wvd[j+k];
    }
    oad[m]=acc;
  }
}

// ---------- fused per-dst GAT (shifted-rowptr convention) ----------
__global__ void kfused(const int* __restrict__ rp, const int* __restrict__ srcs,
                       const float* __restrict__ as_, const float* __restrict__ ad_,
                       const u16* __restrict__ x, const float* __restrict__ W,
                       u32* __restrict__ xn, int Nd, int base0){
  int d=blockIdx.x*blockDim.x+threadIdx.x;
  if(d>=Nd) return;
  int b1=rp[d];
  int b0=d? rp[d-1] : base0;
  if(b0==b1) return;
  float adv=ad_[d];
  float m=-3.4e38f;
  for(int e=b0;e<b1;++e){
    float ev=as_[srcs[e]]+adv;
    ev = ev>=0.f ? ev : 0.2f*ev;
    m=fmaxf(m,ev);
  }
  float s=0.f;
  float z[64];
  #pragma unroll
  for(int k=0;k<64;++k) z[k]=0.f;
  for(int e=b0;e<b1;++e){
    int sr=srcs[e];
    float ev=as_[sr]+adv;
    ev = ev>=0.f ? ev : 0.2f*ev;
    float p=__expf(ev-m);
    s+=p;
    const u16* row=x+(long)sr*64;
    #pragma unroll
    for(int j=0;j<64;j+=8){
      float xr[8]; unpack8(row+j,xr);
      #pragma unroll
      for(int k=0;k<8;++k) z[j+k]+=p*xr[k];
    }
  }
  float inv=1.f/(s+1e-16f);
  #pragma unroll
  for(int k=0;k<64;++k) z[k]*=inv;
  u32* xrow=xn+(long)d*32;
  for(int j0=0;j0<64;j0+=8){
    float acc[8];
    #pragma unroll
    for(int jj=0;jj<8;++jj) acc[jj]=0.f;
    #pragma unroll
    for(int k=0;k<64;++k){
      const float4* W4=(const float4*)(W+k*64+j0);
      float4 wa=W4[0], wb=W4[1];
      float zk=z[k];
      acc[0]+=zk*wa.x; acc[1]+=zk*wa.y; acc[2]+=zk*wa.z; acc[3]+=zk*wa.w;
      acc[4]+=zk*wb.x; acc[5]+=zk*wb.y; acc[6]+=zk*wb.z; acc[7]+=zk*wb.w;
    }
    uint4 old=*(uint4*)(xrow+(j0>>1));
    uint4 pk;
    pk.x=(u32)f2bf(bf2f(old.x&0xffffu)+acc[0])|((u32)f2bf(bf2f(old.x>>16)+acc[1])<<16);
    pk.y=(u32)f2bf(bf2f(old.y&0xffffu)+acc[2])|((u32)f2bf(bf2f(old.y>>16)+acc[3])<<16);
    pk.z=(u32)f2bf(bf2f(old.z&0xffffu)+acc[4])|((u32)f2bf(bf2f(old.z>>16)+acc[5])<<16);
    pk.w=(u32)f2bf(bf2f(old.w&0xffffu)+acc[6])|((u32)f2bf(bf2f(old.w>>16)+acc[7])<<16);
    *(uint4*)(xrow+(j0>>1))=pk;
  }
}

// x = relu(xn_bf16 + bsum) -> bf16; optionally re-zero xn
__global__ void kreluF(u32* __restrict__ xn, const float* __restrict__ bsum,
                       u16* __restrict__ xo, long n64, int dozero){
  long i=((long)blockIdx.x*blockDim.x+threadIdx.x)*4;
  if(i>=n64) return;
  uint2 w=*(uint2*)(xn+(i>>1));
  int j=(int)(i&63);
  float a0=fmaxf(bf2f(w.x&0xffffu)+bsum[j+0],0.f);
  float a1=fmaxf(bf2f(w.x>>16)   +bsum[j+1],0.f);
  float a2=fmaxf(bf2f(w.y&0xffffu)+bsum[j+2],0.f);
  float a3=fmaxf(bf2f(w.y>>16)   +bsum[j+3],0.f);
  uint2 pk;
  pk.x=(u32)f2bf(a0)|((u32)f2bf(a1)<<16);
  pk.y=(u32)f2bf(a2)|((u32)f2bf(a3)<<16);
  *(uint2*)(xo+i)=pk;
  if(dozero){ uint2 z; z.x=0u; z.y=0u; *(uint2*)(xn+(i>>1))=z; }
}

// classifier
__global__ void kcls(const u16* __restrict__ tx, const float* __restrict__ W1,
                     const float* __restrict__ b1, const float* __restrict__ W2,
                     const float* __restrict__ b2, float* __restrict__ out, int N){
  int n=blockIdx.x*blockDim.x+threadIdx.x;
  if(n>=N) return;
  const u16* row=tx+(long)n*64;
  float xr[64];
  #pragma unroll
  for(int j=0;j<64;j+=8) unpack8(row+j,xr+j);
  float acc2=0.f;
  for(int j=0;j<64;++j){
    float a=b1[j];
    #pragma unroll
    for(int k=0;k<64;++k) a += xr[k]*W1[k*64+j];
    a=fmaxf(a,0.f);
    acc2 += a*W2[j];
  }
  float zv=acc2+b2[0];
  out[n]=1.f/(1.f+__expf(-zv));
}

// ---------- pooling: sorted batch -> contiguous group ranges ----------
__global__ void kgrp(const int* __restrict__ batch, int* __restrict__ grp, int N){
  int g=blockIdx.x*blockDim.x+threadIdx.x;
  if(g>1024) return;
  if(g==1024){ grp[1024]=N; return; }
  // lower bound: first n with batch[n] >= g
  int lo=0, hi=N;
  while(lo<hi){ int mid=(lo+hi)>>1; if(batch[mid]<g) lo=mid+1; else hi=mid; }
  grp[g]=lo;
}
// one block per group: reduce mean/max over contiguous rows, then pooled GEMM
__global__ void kpoolf(const u16* __restrict__ tx, const int* __restrict__ grp,
                       const float* __restrict__ pW, const float* __restrict__ pb,
                       float* __restrict__ out){
  __shared__ float S[256], M[256], V[128];
  int g=blockIdx.x, t=threadIdx.x, w=t>>6, j=t&63;
  int n0=grp[g], n1=grp[g+1];
  float s=0.f, m=-3.4e38f;
  for(int n=n0+w; n<n1; n+=4){
    float v=bf2f(tx[(long)n*64+j]);
    s+=v; m=fmaxf(m,v);
  }
  S[t]=s; M[t]=m; __syncthreads();
  if(t<64){
    float ss=S[t]+S[t+64]+S[t+128]+S[t+192];
    float mm=fmaxf(fmaxf(M[t],M[t+64]),fmaxf(M[t+128],M[t+192]));
    int cnt=n1-n0;
    V[t]=ss/fmaxf((float)cnt,1.f);
    V[64+t]=(cnt>0)?mm:0.f;
  }
  __syncthreads();
  if(t<64){
    float acc=pb[t];
    for(int k=0;k<128;++k) acc+=V[k]*pW[k*64+t];
    out[(long)g*64+t]=acc;
  }
}

// ---------- host ----------
extern "C" void kernel_launch(void* const* d_in, const int* in_sizes, int n_in,
                              void* d_out, int out_size, void* d_ws, size_t ws_size,
                              hipStream_t stream){
  const int   NN[6]={100000,150000,500000,20000,5000,50000};
  const long  XO[6]={0,100000,250000,750000,770000,775000};
  const int   RS[12]={0,1,2,2,2,2,1,2,3,4,5,2};
  const int   RD[12]={1,2,3,4,5,2,0,1,2,2,2,2};
  const int   EC[12]={150000,500000,500000,500000,500000,500000,150000,500000,500000,500000,500000,500000};

  const float* xin[6];  for(int t=0;t<6;++t) xin[t]=(const float*)d_in[t];
  const float* embW[6]; const float* embB[6];
  for(int t=0;t<6;++t){ embW[t]=(const float*)d_in[6+2*t]; embB[t]=(const float*)d_in[7+2*t]; }
  const float* gatW =(const float*)d_in[18];
  const float* gatAs=(const float*)d_in[19];
  const float* gatAd=(const float*)d_in[20];
  const float* gatB =(const float*)d_in[21];
  const float* poolW=(const float*)d_in[22];
  const float* poolB=(const float*)d_in[23];
  const float* W1=(const float*)d_in[24];
  const float* b1=(const float*)d_in[25];
  const float* W2=(const float*)d_in[26];
  const float* b2=(const float*)d_in[27];
  const int* esrc[12]; const int* edst[12];
  for(int r=0;r<12;++r){ esrc[r]=(const int*)d_in[28+2*r]; edst[r]=(const int*)d_in[29+2*r]; }
  const int* batch=(const int*)d_in[52];
  float* out=(float*)d_out;
  (void)in_sizes; (void)n_in;

  // concat offsets
  EdgeTab et;
  int rpo=0, seo=0;
  for(int r=0;r<12;++r){
    et.dst[r]=edst[r]; et.src[r]=esrc[r];
    et.seo[r]=seo; et.rpo[r]=rpo;
    et.nd[r]=NN[RD[r]]; et.ns[r]=NN[RS[r]];
    seo+=EC[r]; rpo+=NN[RD[r]]+1;
  }
  et.seo[12]=seo; et.rpo[12]=rpo;
  const int Etot=seo;        // 5,300,000
  const int RPtot=rpo;       // 3,475,012

  // ---- workspace layout (~248 MB) ----
  char* w=(char*)d_ws;
  size_t off=0;
  auto take=[&](size_t bytes)->void*{
    void* p=w+off; off+=(bytes+(size_t)255)&~(size_t)255; return p;
  };
  u16*   X    =(u16*)  take(105600000);
  u32*   XN   =(u32*)  take(105600000);
  int*   RP   =(int*)  take((size_t)RPtot*4);
  int*   SRCS =(int*)  take((size_t)Etot*4);
  int*   BS   =(int*)  take(4096);
  float* ASRC =(float*)take(2000000);
  float* ADST =(float*)take(2000000);
  float* BSUM =(float*)take(4608);
  int*   GRP  =(int*)  take(4104);
  size_t need=off;

  const int B=256;

  if(ws_size<need){
    kdiag<<<CDIV(out_size,B),B,0,stream>>>(out,out_size,(float)(ws_size>>20));
    return;
  }

  // ---- CSR build: 6 dispatches ----
  int nb=CDIV(RPtot,4096);
  kzeroi<<<CDIV(RPtot,B),B,0,stream>>>(RP,RPtot);
  khistAll<<<CDIV(Etot,B),B,0,stream>>>(et,RP,Etot);
  kscan1<<<nb,256,0,stream>>>(RP,RP,BS,RPtot);      // in-place ok (reads then writes same idx)
  kscan2b<<<1,256,0,stream>>>(BS,nb);
  kscan3<<<CDIV(RPtot,B),B,0,stream>>>(RP,BS,RPtot);
  kscatterAll<<<CDIV(Etot,B),B,0,stream>>>(et,RP,SRCS,Etot);

  // zero XN; bias sums
  kzero4<<<CDIV(6600000L,(long)B),B,0,stream>>>((float4*)XN,6600000L);
  kbsum<<<18,64,0,stream>>>(gatB,BSUM);

  // embeddings
  kemb< 8><<<CDIV(NN[0],B),B,0,stream>>>(xin[0],embW[0],embB[0],X+XO[0]*64,NN[0]);
  kemb< 6><<<CDIV(NN[1],B),B,0,stream>>>(xin[1],embW[1],embB[1],X+XO[1]*64,NN[1]);
  kemb<12><<<CDIV(NN[2],B),B,0,stream>>>(xin[2],embW[2],embB[2],X+XO[2]*64,NN[2]);
  kemb< 6><<<CDIV(NN[3],B),B,0,stream>>>(xin[3],embW[3],embB[3],X+XO[3]*64,NN[3]);
  kemb< 5><<<CDIV(NN[4],B),B,0,stream>>>(xin[4],embW[4],embB[4],X+XO[4]*64,NN[4]);
  kemb< 5><<<CDIV(NN[5],B),B,0,stream>>>(xin[5],embW[5],embB[5],X+XO[5]*64,NN[5]);

  for(int l=0;l<3;++l){
    for(int r=0;r<12;++r){
      int st=RS[r], dt=RD[r];
      const float* Wlr=gatW+(long)(l*12+r)*4096;
      const float* aslr=gatAs+(long)(l*12+r)*64;
      const float* adlr=gatAd+(long)(l*12+r)*64;
      kalphaF<<<CDIV(NN[st]+NN[dt],B),B,0,stream>>>(X+XO[st]*64,X+XO[dt]*64,Wlr,aslr,adlr,
                                                    ASRC,ADST,NN[st],NN[dt]);
      kfused<<<CDIV(NN[dt],B),B,0,stream>>>(RP+et.rpo[r],SRCS,ASRC,ADST,
                                            X+XO[st]*64,Wlr,XN+XO[dt]*32,NN[dt],et.seo[r]);
    }
    for(int t=0;t<6;++t){
      long n64=(long)NN[t]*64;
      kreluF<<<CDIV(n64/4,(long)B),B,0,stream>>>(XN+XO[t]*32,BSUM+(l*6+t)*64,X+XO[t]*64,n64,(l<2)?1:0);
    }
  }

  // classifier
  kcls<<<CDIV(NN[2],B),B,0,stream>>>(X+XO[2]*64,W1,b1,W2,b2,out,NN[2]);

  // pooling (no atomics)
  kgrp<<<CDIV(1025,B),B,0,stream>>>(batch,GRP,NN[2]);
  kpoolf<<<1024,256,0,stream>>>(X+XO[2]*64,GRP,poolW,poolB,out+500000);
}

// Round 7
// 3569.727 us; speedup vs baseline: 9.9576x; 1.6926x over previous
//
#include <hip/hip_runtime.h>
#include <hip/hip_bf16.h>

typedef unsigned int u32;
typedef unsigned short u16;
typedef float f32x4 __attribute__((ext_vector_type(4)));
typedef short bf16x8 __attribute__((ext_vector_type(8)));

#define CDIV(a,b) (((a)+(b)-1)/(b))

// ---------- helpers ----------
__device__ __forceinline__ float bf2f(u32 h){ return __uint_as_float(h<<16); }
__device__ __forceinline__ u16 f2bf(float f){
  u32 u=__float_as_uint(f);
  return (u16)((u + 0x7fffu + ((u>>16)&1u))>>16);   // RNE
}
__device__ __forceinline__ void unpack8(const u16* p, float* xr){
  uint4 v=*(const uint4*)p;
  xr[0]=bf2f(v.x&0xffffu); xr[1]=bf2f(v.x>>16);
  xr[2]=bf2f(v.y&0xffffu); xr[3]=bf2f(v.y>>16);
  xr[4]=bf2f(v.z&0xffffu); xr[5]=bf2f(v.z>>16);
  xr[6]=bf2f(v.w&0xffffu); xr[7]=bf2f(v.w>>16);
}
__device__ __forceinline__ int iclamp(int i, int n){
  unsigned u=(unsigned)i; return (u>=(unsigned)n)?0:i;
}

struct EdgeTab {
  const int* dst[12];
  const int* src[12];
  int seo[13];
  int rpo[13];
  int nd[12];
  int ns[12];
};

// ---------- misc ----------
__global__ void kdiag(float* out, int n, float v){
  int i=blockIdx.x*blockDim.x+threadIdx.x;
  if(i<n) out[i]=(i==0)?v:0.f;
}
__global__ void kzero4(float4* p, long n4){
  long i=(long)blockIdx.x*blockDim.x+threadIdx.x;
  if(i<n4){ float4 z; z.x=z.y=z.z=z.w=0.f; p[i]=z; }
}
__global__ void kzeroi(int* p, int n){
  int i=blockIdx.x*blockDim.x+threadIdx.x;
  if(i<n) p[i]=0;
}
__global__ void kbsum(const float* __restrict__ gb, float* __restrict__ bsum){
  int l=blockIdx.x/6, t=blockIdx.x%6, j=threadIdx.x;
  const int rd[12]={1,2,3,4,5,2,0,1,2,2,2,2};
  float a=0.f;
  #pragma unroll
  for(int r=0;r<12;++r) if(rd[r]==t) a += gb[(l*12+r)*64 + j];
  bsum[(l*6+t)*64 + j]=a;
}
// W[l,r][k][j] f32 -> WT[l*12+r][j*64+k] bf16
__global__ void kwconv(const float* __restrict__ gw, u16* __restrict__ wt, int total){
  int o=blockIdx.x*blockDim.x+threadIdx.x;
  if(o>=total) return;
  int m=o>>12, rem=o&4095, j=rem>>6, k=rem&63;
  wt[o]=f2bf(gw[(m<<12)+(k<<6)+j]);
}

// ---------- CSR build ----------
__global__ void khistAll(EdgeTab et, int* __restrict__ RP, int Etot){
  int i=blockIdx.x*blockDim.x+threadIdx.x;
  if(i>=Etot) return;
  int r=0;
  #pragma unroll
  for(int k=1;k<12;++k) r += (i>=et.seo[k]) ? 1 : 0;
  int e=i-et.seo[r];
  int d=iclamp(et.dst[r][e], et.nd[r]);
  atomicAdd(RP+et.rpo[r]+d,1);
}
__global__ void kscan1(const int* __restrict__ hist, int* __restrict__ rp, int* __restrict__ bsum, int N){
  __shared__ int lds[256];
  __shared__ int pref[256];
  int b=blockIdx.x, t=threadIdx.x;
  int base=b*4096+t*16;
  int v[16]; int s=0;
  #pragma unroll
  for(int k=0;k<16;++k){ int idx=base+k; v[k]=(idx<N)?hist[idx]:0; s+=v[k]; }
  lds[t]=s; __syncthreads();
  if(t==0){ int run=0; for(int i=0;i<256;++i){ pref[i]=run; run+=lds[i]; } bsum[b]=run; }
  __syncthreads();
  int run=pref[t];
  #pragma unroll
  for(int k=0;k<16;++k){ int idx=base+k; if(idx<N) rp[idx]=run; run+=v[k]; }
}
__global__ void kscan2b(int* bsum, int nb){
  __shared__ int lds[256], pref[256], tot;
  int t=threadIdx.x;
  int v[4]; int s=0;
  #pragma unroll
  for(int k=0;k<4;++k){ int idx=t*4+k; v[k]=(idx<nb)?bsum[idx]:0; s+=v[k]; }
  lds[t]=s; __syncthreads();
  if(t==0){ int run=0; for(int i=0;i<256;++i){ pref[i]=run; run+=lds[i]; } tot=run; }
  __syncthreads();
  int run=pref[t];
  #pragma unroll
  for(int k=0;k<4;++k){ int idx=t*4+k; if(idx<nb){ int x=v[k]; bsum[idx]=run; run+=x; } }
  if(t==0) bsum[nb]=tot;
}
__global__ void kscan3(int* __restrict__ rp, const int* __restrict__ bsum, int N){
  int i=blockIdx.x*blockDim.x+threadIdx.x;
  if(i<N) rp[i]+=bsum[i>>12];
}
__global__ void kscatterAll(EdgeTab et, int* __restrict__ RP, int* __restrict__ SRCS, int Etot){
  int i=blockIdx.x*blockDim.x+threadIdx.x;
  if(i>=Etot) return;
  int r=0;
  #pragma unroll
  for(int k=1;k<12;++k) r += (i>=et.seo[k]) ? 1 : 0;
  int e=i-et.seo[r];
  int d=iclamp(et.dst[r][e], et.nd[r]);
  int pos=atomicAdd(RP+et.rpo[r]+d,1);
  SRCS[pos]=iclamp(et.src[r][e], et.ns[r]);
}

// ---------- embeddings ----------
template<int D>
__global__ void kemb(const float* __restrict__ xin, const float* __restrict__ W,
                     const float* __restrict__ b, u16* __restrict__ xout, int N){
  int n=blockIdx.x*blockDim.x+threadIdx.x;
  if(n>=N) return;
  float xr[D];
  #pragma unroll
  for(int k=0;k<D;++k) xr[k]=xin[(long)n*D+k];
  u16* orow=xout+(long)n*64;
  for(int j0=0;j0<64;j0+=8){
    float acc[8];
    #pragma unroll
    for(int jj=0;jj<8;++jj){
      float a=b[j0+jj];
      #pragma unroll
      for(int k=0;k<D;++k) a += xr[k]*W[k*64+j0+jj];
      acc[jj]=a;
    }
    uint4 pk;
    pk.x=(u32)f2bf(acc[0])|((u32)f2bf(acc[1])<<16);
    pk.y=(u32)f2bf(acc[2])|((u32)f2bf(acc[3])<<16);
    pk.z=(u32)f2bf(acc[4])|((u32)f2bf(acc[5])<<16);
    pk.w=(u32)f2bf(acc[6])|((u32)f2bf(acc[7])<<16);
    *(uint4*)(orow+j0)=pk;
  }
}

// fused src+dst alpha
__global__ void kalphaF(const u16* __restrict__ xs_, const u16* __restrict__ xd_,
                        const float* __restrict__ W,
                        const float* __restrict__ av_s, const float* __restrict__ av_d,
                        float* __restrict__ oas, float* __restrict__ oad, int Ns, int Nd){
  __shared__ float wvs[64], wvd[64];
  int t=threadIdx.x;
  if(t<64){
    float a=0.f,b=0.f;
    for(int j=0;j<64;++j){ float wv=W[t*64+j]; a+=wv*av_s[j]; b+=wv*av_d[j]; }
    wvs[t]=a; wvd[t]=b;
  }
  __syncthreads();
  int n=blockIdx.x*blockDim.x+t;
  if(n<Ns){
    const u16* row=xs_+(long)n*64;
    float acc=0.f;
    #pragma unroll
    for(int j=0;j<64;j+=8){
      float xr[8]; unpack8(row+j,xr);
      #pragma unroll
      for(int k=0;k<8;++k) acc += xr[k]*wvs[j+k];
    }
    oas[n]=acc;
  } else if(n<Ns+Nd){
    int m=n-Ns;
    const u16* row=xd_+(long)m*64;
    float acc=0.f;
    #pragma unroll
    for(int j=0;j<64;j+=8){
      float xr[8]; unpack8(row+j,xr);
      #pragma unroll
      for(int k=0;k<8;++k) acc += xr[k]*wvd[j+k];
    }
    oad[m]=acc;
  }
}

// ---------- fused GAT, MFMA version ----------
// block = 256 thr = 4 waves, 64 dst nodes. LDS: z-bf16 8KB | WT-bf16 8KB | C-f32 16KB
#define LZ 0
#define LW 8192
#define LC 16384
__global__ void kfusedM(const int* __restrict__ rp, const int* __restrict__ srcs,
                        const float* __restrict__ as_, const float* __restrict__ ad_,
                        const u16* __restrict__ x, const u16* __restrict__ wt,
                        u32* __restrict__ xn, int Nd, int base0){
  __shared__ char L[32768];
  int t=threadIdx.x;
  int d0=blockIdx.x*64;

  // stage WT (row j=128B, 64 k bf16) -> LDS with per-16B XOR swizzle
  {
    const uint4* s4=(const uint4*)wt;
    uint4 v0=s4[t*2], v1=s4[t*2+1];
    int b0=t*32, j=b0>>7;
    *(uint4*)(L+LW+((b0   )^((j&7)<<4)))=v0;
    *(uint4*)(L+LW+((b0+16)^((j&7)<<4)))=v1;
  }

  // phase 1: online-softmax aggregation; 4 threads per node (feature quarters)
  int n=t&63, q=t>>6;
  int d=d0+n;
  float z[16];
  #pragma unroll
  for(int k=0;k<16;++k) z[k]=0.f;
  float sden=0.f;
  if(d<Nd){
    int b1=rp[d], b0e= d? rp[d-1]:base0;
    float adv=ad_[d];
    float m=-3.4e38f;
    for(int e=b0e;e<b1;++e){
      int sr=srcs[e];
      float ev=as_[sr]+adv;
      ev = ev>=0.f?ev:0.2f*ev;
      float p;
      if(ev>m){
        float sc=__expf(m-ev);
        sden*=sc;
        #pragma unroll
        for(int k=0;k<16;++k) z[k]*=sc;
        m=ev; p=1.f;
      } else p=__expf(ev-m);
      sden+=p;
      const u16* row=x+(long)sr*64+q*16;
      float xr[8];
      unpack8(row,xr);
      #pragma unroll
      for(int k=0;k<8;++k) z[k]+=p*xr[k];
      unpack8(row+8,xr);
      #pragma unroll
      for(int k=0;k<8;++k) z[8+k]+=p*xr[k];
    }
  }
  float inv=1.f/(sden+1e-16f);
  {
    uint4 p0,p1;
    p0.x=(u32)f2bf(z[0]*inv) |((u32)f2bf(z[1]*inv)<<16);
    p0.y=(u32)f2bf(z[2]*inv) |((u32)f2bf(z[3]*inv)<<16);
    p0.z=(u32)f2bf(z[4]*inv) |((u32)f2bf(z[5]*inv)<<16);
    p0.w=(u32)f2bf(z[6]*inv) |((u32)f2bf(z[7]*inv)<<16);
    p1.x=(u32)f2bf(z[8]*inv) |((u32)f2bf(z[9]*inv)<<16);
    p1.y=(u32)f2bf(z[10]*inv)|((u32)f2bf(z[11]*inv)<<16);
    p1.z=(u32)f2bf(z[12]*inv)|((u32)f2bf(z[13]*inv)<<16);
    p1.w=(u32)f2bf(z[14]*inv)|((u32)f2bf(z[15]*inv)<<16);
    int zb=n*128+q*32;
    *(uint4*)(L+LZ+((zb   )^((n&7)<<4)))=p0;
    *(uint4*)(L+LZ+((zb+16)^((n&7)<<4)))=p1;
  }
  __syncthreads();

  // phase 2: MFMA. wave w handles node tile nt=w*16; out 16x64, K=64
  {
    int w=t>>6, l=t&63;
    int nt=w*16;
    f32x4 acc[4];
    #pragma unroll
    for(int ct=0;ct<4;++ct){ acc[ct][0]=0.f; acc[ct][1]=0.f; acc[ct][2]=0.f; acc[ct][3]=0.f; }
    int arow=nt+(l&15);
    int kb=(l>>4)*8;
    #pragma unroll
    for(int ks=0;ks<64;ks+=32){
      int ab=arow*128+(ks+kb)*2;
      uint4 av=*(uint4*)(L+LZ+(ab^((arow&7)<<4)));
      bf16x8 af=*(bf16x8*)&av;
      #pragma unroll
      for(int ct=0;ct<4;++ct){
        int jrow=ct*16+(l&15);
        int bb=jrow*128+(ks+kb)*2;
        uint4 bv=*(uint4*)(L+LW+(bb^((jrow&7)<<4)));
        bf16x8 bfr=*(bf16x8*)&bv;
        acc[ct]=__builtin_amdgcn_mfma_f32_16x16x32_bf16(af,bfr,acc[ct],0,0,0);
      }
    }
    // C store to LDS: lane l, reg r -> row nt+(l>>4)*4+r, col ct*16+(l&15)
    #pragma unroll
    for(int ct=0;ct<4;++ct){
      #pragma unroll
      for(int r=0;r<4;++r){
        int crow=nt+(l>>4)*4+r;
        int ccol=ct*16+(l&15);
        int cb=crow*256+ccol*4;
        *(float*)(L+LC+(cb^((crow&7)<<4)))=acc[ct][r];
      }
    }
  }
  __syncthreads();

  // epilogue: thread -> node nn=t>>2, col-quarter cq=t&3; RMW 16 bf16 of XN
  {
    int nn=t>>2, cq=t&3;
    if(d0+nn<Nd){
      float cv[16];
      #pragma unroll
      for(int p=0;p<4;++p){
        int cb=nn*256+cq*64+p*16;
        uint4 v=*(uint4*)(L+LC+(cb^((nn&7)<<4)));
        const float* f=(const float*)&v;
        cv[p*4+0]=f[0]; cv[p*4+1]=f[1]; cv[p*4+2]=f[2]; cv[p*4+3]=f[3];
      }
      u32* xrow=xn+(long)(d0+nn)*32+cq*8;
      uint4 o0=*(uint4*)xrow;
      uint4 o1=*(uint4*)(xrow+4);
      u32 wd[8]={o0.x,o0.y,o0.z,o0.w,o1.x,o1.y,o1.z,o1.w};
      #pragma unroll
      for(int i=0;i<8;++i){
        float lo=bf2f(wd[i]&0xffffu)+cv[2*i];
        float hi=bf2f(wd[i]>>16)+cv[2*i+1];
        wd[i]=(u32)f2bf(lo)|((u32)f2bf(hi)<<16);
      }
      uint4 s0; s0.x=wd[0]; s0.y=wd[1]; s0.z=wd[2]; s0.w=wd[3];
      uint4 s1; s1.x=wd[4]; s1.y=wd[5]; s1.z=wd[6]; s1.w=wd[7];
      *(uint4*)xrow=s0;
      *(uint4*)(xrow+4)=s1;
    }
  }
}

// x = relu(xn_bf16 + bsum) -> bf16; optionally re-zero xn
__global__ void kreluF(u32* __restrict__ xn, const float* __restrict__ bsum,
                       u16* __restrict__ xo, long n64, int dozero){
  long i=((long)blockIdx.x*blockDim.x+threadIdx.x)*4;
  if(i>=n64) return;
  uint2 w=*(uint2*)(xn+(i>>1));
  int j=(int)(i&63);
  float a0=fmaxf(bf2f(w.x&0xffffu)+bsum[j+0],0.f);
  float a1=fmaxf(bf2f(w.x>>16)   +bsum[j+1],0.f);
  float a2=fmaxf(bf2f(w.y&0xffffu)+bsum[j+2],0.f);
  float a3=fmaxf(bf2f(w.y>>16)   +bsum[j+3],0.f);
  uint2 pk;
  pk.x=(u32)f2bf(a0)|((u32)f2bf(a1)<<16);
  pk.y=(u32)f2bf(a2)|((u32)f2bf(a3)<<16);
  *(uint2*)(xo+i)=pk;
  if(dozero){ uint2 z; z.x=0u; z.y=0u; *(uint2*)(xn+(i>>1))=z; }
}

// classifier
__global__ void kcls(const u16* __restrict__ tx, const float* __restrict__ W1,
                     const float* __restrict__ b1, const float* __restrict__ W2,
                     const float* __restrict__ b2, float* __restrict__ out, int N){
  int n=blockIdx.x*blockDim.x+threadIdx.x;
  if(n>=N) return;
  const u16* row=tx+(long)n*64;
  float xr[64];
  #pragma unroll
  for(int j=0;j<64;j+=8) unpack8(row+j,xr+j);
  float acc2=0.f;
  for(int j=0;j<64;++j){
    float a=b1[j];
    #pragma unroll
    for(int k=0;k<64;++k) a += xr[k]*W1[k*64+j];
    a=fmaxf(a,0.f);
    acc2 += a*W2[j];
  }
  float zv=acc2+b2[0];
  out[n]=1.f/(1.f+__expf(-zv));
}

// ---------- pooling ----------
__global__ void kgrp(const int* __restrict__ batch, int* __restrict__ grp, int N){
  int g=blockIdx.x*blockDim.x+threadIdx.x;
  if(g>1024) return;
  if(g==1024){ grp[1024]=N; return; }
  int lo=0, hi=N;
  while(lo<hi){ int mid=(lo+hi)>>1; if(batch[mid]<g) lo=mid+1; else hi=mid; }
  grp[g]=lo;
}
__global__ void kpoolf(const u16* __restrict__ tx, const int* __restrict__ grp,
                       const float* __restrict__ pW, const float* __restrict__ pb,
                       float* __restrict__ out){
  __shared__ float S[256], M[256], V[128];
  int g=blockIdx.x, t=threadIdx.x, w=t>>6, j=t&63;
  int n0=grp[g], n1=grp[g+1];
  float s=0.f, m=-3.4e38f;
  for(int n=n0+w; n<n1; n+=4){
    float v=bf2f(tx[(long)n*64+j]);
    s+=v; m=fmaxf(m,v);
  }
  S[t]=s; M[t]=m; __syncthreads();
  if(t<64){
    float ss=S[t]+S[t+64]+S[t+128]+S[t+192];
    float mm=fmaxf(fmaxf(M[t],M[t+64]),fmaxf(M[t+128],M[t+192]));
    int cnt=n1-n0;
    V[t]=ss/fmaxf((float)cnt,1.f);
    V[64+t]=(cnt>0)?mm:0.f;
  }
  __syncthreads();
  if(t<64){
    float acc=pb[t];
    for(int k=0;k<128;++k) acc+=V[k]*pW[k*64+t];
    out[(long)g*64+t]=acc;
  }
}

// ---------- host ----------
extern "C" void kernel_launch(void* const* d_in, const int* in_sizes, int n_in,
                              void* d_out, int out_size, void* d_ws, size_t ws_size,
                              hipStream_t stream){
  const int   NN[6]={100000,150000,500000,20000,5000,50000};
  const long  XO[6]={0,100000,250000,750000,770000,775000};
  const int   RS[12]={0,1,2,2,2,2,1,2,3,4,5,2};
  const int   RD[12]={1,2,3,4,5,2,0,1,2,2,2,2};
  const int   EC[12]={150000,500000,500000,500000,500000,500000,150000,500000,500000,500000,500000,500000};

  const float* xin[6];  for(int t=0;t<6;++t) xin[t]=(const float*)d_in[t];
  const float* embW[6]; const float* embB[6];
  for(int t=0;t<6;++t){ embW[t]=(const float*)d_in[6+2*t]; embB[t]=(const float*)d_in[7+2*t]; }
  const float* gatW =(const float*)d_in[18];
  const float* gatAs=(const float*)d_in[19];
  const float* gatAd=(const float*)d_in[20];
  const float* gatB =(const float*)d_in[21];
  const float* poolW=(const float*)d_in[22];
  const float* poolB=(const float*)d_in[23];
  const float* W1=(const float*)d_in[24];
  const float* b1=(const float*)d_in[25];
  const float* W2=(const float*)d_in[26];
  const float* b2=(const float*)d_in[27];
  const int* esrc[12]; const int* edst[12];
  for(int r=0;r<12;++r){ esrc[r]=(const int*)d_in[28+2*r]; edst[r]=(const int*)d_in[29+2*r]; }
  const int* batch=(const int*)d_in[52];
  float* out=(float*)d_out;
  (void)in_sizes; (void)n_in;

  EdgeTab et;
  int rpo=0, seo=0;
  for(int r=0;r<12;++r){
    et.dst[r]=edst[r]; et.src[r]=esrc[r];
    et.seo[r]=seo; et.rpo[r]=rpo;
    et.nd[r]=NN[RD[r]]; et.ns[r]=NN[RS[r]];
    seo+=EC[r]; rpo+=NN[RD[r]]+1;
  }
  et.seo[12]=seo; et.rpo[12]=rpo;
  const int Etot=seo;
  const int RPtot=rpo;

  // ---- workspace (~251 MB) ----
  char* w=(char*)d_ws;
  size_t off=0;
  auto take=[&](size_t bytes)->void*{
    void* p=w+off; off+=(bytes+(size_t)255)&~(size_t)255; return p;
  };
  u16*   X    =(u16*)  take(105600000);
  u32*   XN   =(u32*)  take(105600000);
  int*   RP   =(int*)  take((size_t)RPtot*4);
  int*   SRCS =(int*)  take((size_t)Etot*4);
  int*   BS   =(int*)  take(4096);
  float* ASRC =(float*)take(2000000);
  float* ADST =(float*)take(2000000);
  float* BSUM =(float*)take(4608);
  int*   GRP  =(int*)  take(4104);
  u16*   WT   =(u16*)  take(294912);      // 36 x 64x64 bf16, [j][k]
  size_t need=off;

  const int B=256;

  if(ws_size<need){
    kdiag<<<CDIV(out_size,B),B,0,stream>>>(out,out_size,(float)(ws_size>>20));
    return;
  }

  // CSR build
  int nb=CDIV(RPtot,4096);
  kzeroi<<<CDIV(RPtot,B),B,0,stream>>>(RP,RPtot);
  khistAll<<<CDIV(Etot,B),B,0,stream>>>(et,RP,Etot);
  kscan1<<<nb,256,0,stream>>>(RP,RP,BS,RPtot);
  kscan2b<<<1,256,0,stream>>>(BS,nb);
  kscan3<<<CDIV(RPtot,B),B,0,stream>>>(RP,BS,RPtot);
  kscatterAll<<<CDIV(Etot,B),B,0,stream>>>(et,RP,SRCS,Etot);

  // weights prep + XN zero + bias sums
  kwconv<<<CDIV(147456,B),B,0,stream>>>(gatW,WT,147456);
  kzero4<<<CDIV(6600000L,(long)B),B,0,stream>>>((float4*)XN,6600000L);
  kbsum<<<18,64,0,stream>>>(gatB,BSUM);

  // embeddings
  kemb< 8><<<CDIV(NN[0],B),B,0,stream>>>(xin[0],embW[0],embB[0],X+XO[0]*64,NN[0]);
  kemb< 6><<<CDIV(NN[1],B),B,0,stream>>>(xin[1],embW[1],embB[1],X+XO[1]*64,NN[1]);
  kemb<12><<<CDIV(NN[2],B),B,0,stream>>>(xin[2],embW[2],embB[2],X+XO[2]*64,NN[2]);
  kemb< 6><<<CDIV(NN[3],B),B,0,stream>>>(xin[3],embW[3],embB[3],X+XO[3]*64,NN[3]);
  kemb< 5><<<CDIV(NN[4],B),B,0,stream>>>(xin[4],embW[4],embB[4],X+XO[4]*64,NN[4]);
  kemb< 5><<<CDIV(NN[5],B),B,0,stream>>>(xin[5],embW[5],embB[5],X+XO[5]*64,NN[5]);

  for(int l=0;l<3;++l){
    for(int r=0;r<12;++r){
      int st=RS[r], dt=RD[r];
      const float* Wlr=gatW+(long)(l*12+r)*4096;
      const float* aslr=gatAs+(long)(l*12+r)*64;
      const float* adlr=gatAd+(long)(l*12+r)*64;
      kalphaF<<<CDIV(NN[st]+NN[dt],B),B,0,stream>>>(X+XO[st]*64,X+XO[dt]*64,Wlr,aslr,adlr,
                                                    ASRC,ADST,NN[st],NN[dt]);
      kfusedM<<<CDIV(NN[dt],64),B,0,stream>>>(RP+et.rpo[r],SRCS,ASRC,ADST,
                                              X+XO[st]*64,WT+(size_t)(l*12+r)*4096,
                                              XN+XO[dt]*32,NN[dt],et.seo[r]);
    }
    for(int t=0;t<6;++t){
      long n64=(long)NN[t]*64;
      kreluF<<<CDIV(n64/4,(long)B),B,0,stream>>>(XN+XO[t]*32,BSUM+(l*6+t)*64,X+XO[t]*64,n64,(l<2)?1:0);
    }
  }

  kcls<<<CDIV(NN[2],B),B,0,stream>>>(X+XO[2]*64,W1,b1,W2,b2,out,NN[2]);

  kgrp<<<CDIV(1025,B),B,0,stream>>>(batch,GRP,NN[2]);
  kpoolf<<<1024,256,0,stream>>>(X+XO[2]*64,GRP,poolW,poolB,out+500000);
}

// Round 8
// 2599.570 us; speedup vs baseline: 13.6738x; 1.3732x over previous
//
#include <hip/hip_runtime.h>
#include <hip/hip_bf16.h>

typedef unsigned int u32;
typedef unsigned short u16;
typedef _Float16 f16;
typedef float f32x4 __attribute__((ext_vector_type(4)));
typedef short bf16x8 __attribute__((ext_vector_type(8)));

#define CDIV(a,b) (((a)+(b)-1)/(b))

// ---------- helpers ----------
__device__ __forceinline__ float bf2f(u32 h){ return __uint_as_float(h<<16); }
__device__ __forceinline__ u16 f2bf(float f){
  u32 u=__float_as_uint(f);
  return (u16)((u + 0x7fffu + ((u>>16)&1u))>>16);   // RNE
}
__device__ __forceinline__ void unpack8(const u16* p, float* xr){
  uint4 v=*(const uint4*)p;
  xr[0]=bf2f(v.x&0xffffu); xr[1]=bf2f(v.x>>16);
  xr[2]=bf2f(v.y&0xffffu); xr[3]=bf2f(v.y>>16);
  xr[4]=bf2f(v.z&0xffffu); xr[5]=bf2f(v.z>>16);
  xr[6]=bf2f(v.w&0xffffu); xr[7]=bf2f(v.w>>16);
}
__device__ __forceinline__ int iclamp(int i, int n){
  unsigned u=(unsigned)i; return (u>=(unsigned)n)?0:i;
}

struct EdgeTab {
  const int* dst[12];
  const int* src[12];
  int seo[13];
  int rpo[13];
  int nd[12];
  int ns[12];
};

// big merged table (passed by value, ~1.1KB)
struct GTab {
  int nn[6]; int xo[6];
  int rst[12];
  int aso[12], ado[12], rpo[12], seo[12];
  int tord[6]; int bofs[7];    // kfusedM2 block ranges (64 nodes/blk)
  int abofs[7];                // kalphaM block ranges (256 nodes/blk)
  int nrel[6], rel[6][6];
  int nrole[6]; int rwv[6][12]; int rofs[6][12];
  int dszb;                    // AA dst-segment base
};

// ---------- misc ----------
__global__ void kdiag(float* out, int n, float v){
  int i=blockIdx.x*blockDim.x+threadIdx.x;
  if(i<n) out[i]=(i==0)?v:0.f;
}
__global__ void kzeroi(int* p, int n){
  int i=blockIdx.x*blockDim.x+threadIdx.x;
  if(i<n) p[i]=0;
}
__global__ void kbsum(const float* __restrict__ gb, float* __restrict__ bsum){
  int l=blockIdx.x/6, t=blockIdx.x%6, j=threadIdx.x;
  const int rd[12]={1,2,3,4,5,2,0,1,2,2,2,2};
  float a=0.f;
  #pragma unroll
  for(int r=0;r<12;++r) if(rd[r]==t) a += gb[(l*12+r)*64 + j];
  bsum[(l*6+t)*64 + j]=a;
}
// W[l,r][k][j] f32 -> WT[l*12+r][j*64+k] bf16
__global__ void kwconv(const float* __restrict__ gw, u16* __restrict__ wt, int total){
  int o=blockIdx.x*blockDim.x+threadIdx.x;
  if(o>=total) return;
  int m=o>>12, rem=o&4095, j=rem>>6, k=rem&63;
  wt[o]=f2bf(gw[(m<<12)+(k<<6)+j]);
}
// wv[(l*12+r)*2+role][k] = sum_j W[l,r][k][j]*a[j]
__global__ void kwv(const float* __restrict__ gw, const float* __restrict__ gas,
                    const float* __restrict__ gad, float* __restrict__ wv){
  int m=blockIdx.x;          // 0..71
  int lr=m>>1, role=m&1;
  int k=threadIdx.x;
  const float* a=(role?gad:gas)+(size_t)lr*64;
  const float* W=gw+(size_t)lr*4096;
  float acc=0.f;
  for(int j=0;j<64;++j) acc += W[k*64+j]*a[j];
  wv[(size_t)m*64+k]=acc;
}

// ---------- CSR build ----------
__global__ void khistAll(EdgeTab et, int* __restrict__ RP, int Etot){
  int i=blockIdx.x*blockDim.x+threadIdx.x;
  if(i>=Etot) return;
  int r=0;
  #pragma unroll
  for(int k=1;k<12;++k) r += (i>=et.seo[k]) ? 1 : 0;
  int e=i-et.seo[r];
  int d=iclamp(et.dst[r][e], et.nd[r]);
  atomicAdd(RP+et.rpo[r]+d,1);
}
__global__ void kscan1(const int* __restrict__ hist, int* __restrict__ rp, int* __restrict__ bsum, int N){
  __shared__ int lds[256];
  __shared__ int pref[256];
  int b=blockIdx.x, t=threadIdx.x;
  int base=b*4096+t*16;
  int v[16]; int s=0;
  #pragma unroll
  for(int k=0;k<16;++k){ int idx=base+k; v[k]=(idx<N)?hist[idx]:0; s+=v[k]; }
  lds[t]=s; __syncthreads();
  if(t==0){ int run=0; for(int i=0;i<256;++i){ pref[i]=run; run+=lds[i]; } bsum[b]=run; }
  __syncthreads();
  int run=pref[t];
  #pragma unroll
  for(int k=0;k<16;++k){ int idx=base+k; if(idx<N) rp[idx]=run; run+=v[k]; }
}
__global__ void kscan2b(int* bsum, int nb){
  __shared__ int lds[256], pref[256], tot;
  int t=threadIdx.x;
  int v[4]; int s=0;
  #pragma unroll
  for(int k=0;k<4;++k){ int idx=t*4+k; v[k]=(idx<nb)?bsum[idx]:0; s+=v[k]; }
  lds[t]=s; __syncthreads();
  if(t==0){ int run=0; for(int i=0;i<256;++i){ pref[i]=run; run+=lds[i]; } tot=run; }
  __syncthreads();
  int run=pref[t];
  #pragma unroll
  for(int k=0;k<4;++k){ int idx=t*4+k; if(idx<nb){ int x=v[k]; bsum[idx]=run; run+=x; } }
  if(t==0) bsum[nb]=tot;
}
__global__ void kscan3(int* __restrict__ rp, const int* __restrict__ bsum, int N){
  int i=blockIdx.x*blockDim.x+threadIdx.x;
  if(i<N) rp[i]+=bsum[i>>12];
}
__global__ void kscatterAll(EdgeTab et, int* __restrict__ RP, int* __restrict__ SRCS, int Etot){
  int i=blockIdx.x*blockDim.x+threadIdx.x;
  if(i>=Etot) return;
  int r=0;
  #pragma unroll
  for(int k=1;k<12;++k) r += (i>=et.seo[k]) ? 1 : 0;
  int e=i-et.seo[r];
  int d=iclamp(et.dst[r][e], et.nd[r]);
  int pos=atomicAdd(RP+et.rpo[r]+d,1);
  SRCS[pos]=iclamp(et.src[r][e], et.ns[r]);
}

// ---------- embeddings ----------
template<int D>
__global__ void kemb(const float* __restrict__ xin, const float* __restrict__ W,
                     const float* __restrict__ b, u16* __restrict__ xout, int N){
  int n=blockIdx.x*blockDim.x+threadIdx.x;
  if(n>=N) return;
  float xr[D];
  #pragma unroll
  for(int k=0;k<D;++k) xr[k]=xin[(long)n*D+k];
  u16* orow=xout+(long)n*64;
  for(int j0=0;j0<64;j0+=8){
    float acc[8];
    #pragma unroll
    for(int jj=0;jj<8;++jj){
      float a=b[j0+jj];
      #pragma unroll
      for(int k=0;k<D;++k) a += xr[k]*W[k*64+j0+jj];
      acc[jj]=a;
    }
    uint4 pk;
    pk.x=(u32)f2bf(acc[0])|((u32)f2bf(acc[1])<<16);
    pk.y=(u32)f2bf(acc[2])|((u32)f2bf(acc[3])<<16);
    pk.z=(u32)f2bf(acc[4])|((u32)f2bf(acc[5])<<16);
    pk.w=(u32)f2bf(acc[6])|((u32)f2bf(acc[7])<<16);
    *(uint4*)(orow+j0)=pk;
  }
}

// ---------- merged alpha: all roles for all nodes, one pass ----------
__global__ void kalphaM(const u16* __restrict__ X, const float* __restrict__ WVl,
                        f16* __restrict__ AA, GTab tab){
  __shared__ float wv[12*64];
  int b=blockIdx.x, tid=threadIdx.x;
  int ti=0;
  #pragma unroll
  for(int k=1;k<6;++k) ti += (b>=tab.abofs[k]) ? 1 : 0;
  int t=tab.tord[ti];
  int nr=tab.nrole[t];
  for(int i=tid;i<nr*64;i+=256){
    int ro=i>>6, j=i&63;
    wv[i]=WVl[tab.rwv[t][ro]*64+j];
  }
  __syncthreads();
  int nid=(b-tab.abofs[ti])*256+tid;
  if(nid>=tab.nn[t]) return;
  const u16* row=X+((long)tab.xo[t]+nid)*64;
  float xr[64];
  #pragma unroll
  for(int j=0;j<64;j+=8) unpack8(row+j,xr+j);
  for(int ro=0;ro<nr;++ro){
    float acc=0.f;
    #pragma unroll
    for(int k=0;k<64;++k) acc += xr[k]*wv[ro*64+k];
    AA[tab.rofs[t][ro]+nid]=(f16)acc;
  }
}

// ---------- merged fused GAT over all relations of the block's dst type ----------
#define LZ 0
#define LW 8192
#define LC 16384
__global__ void kfusedM2(const u16* __restrict__ Xc, u16* __restrict__ Xn,
                         const u16* __restrict__ WTl, const f16* __restrict__ AA,
                         const int* __restrict__ RP, const int* __restrict__ SRCS,
                         const float* __restrict__ BSl, GTab tab){
  __shared__ char L[32768];
  int tid=threadIdx.x;
  int b=blockIdx.x;
  int ti=0;
  #pragma unroll
  for(int k=1;k<6;++k) ti += (b>=tab.bofs[k]) ? 1 : 0;
  int t=tab.tord[ti];
  int d0=(b-tab.bofs[ti])*64;
  int Nt=tab.nn[t];
  int n=tid&63, q=tid>>6;
  int d=d0+n;

  f32x4 acc[4];
  #pragma unroll
  for(int ct=0;ct<4;++ct){ acc[ct][0]=0.f; acc[ct][1]=0.f; acc[ct][2]=0.f; acc[ct][3]=0.f; }

  int nrel=tab.nrel[t];
  for(int ri=0;ri<nrel;++ri){
    int r=tab.rel[t][ri];
    __syncthreads();                       // prev MFMA done with LZ/LW
    // stage WT_r (swizzled)
    {
      const uint4* s4=(const uint4*)(WTl+(size_t)r*4096);
      uint4 v0=s4[tid*2], v1=s4[tid*2+1];
      int b0=tid*32, j=b0>>7;
      *(uint4*)(L+LW+((b0   )^((j&7)<<4)))=v0;
      *(uint4*)(L+LW+((b0+16)^((j&7)<<4)))=v1;
    }
    // phase 1: online-softmax aggregation (4 threads per node)
    float z[16];
    #pragma unroll
    for(int k=0;k<16;++k) z[k]=0.f;
    float sden=0.f;
    if(d<Nt){
      int b1=RP[tab.rpo[r]+d];
      int b0e= d? RP[tab.rpo[r]+d-1] : tab.seo[r];
      float adv=(float)AA[tab.dszb+tab.ado[r]+d];
      const u16* xbase=Xc+(long)tab.xo[tab.rst[r]]*64;
      const f16* asp=AA+tab.aso[r];
      float m=-3.4e38f;
      for(int e=b0e;e<b1;++e){
        int sr=SRCS[e];
        float ev=(float)asp[sr]+adv;
        ev = ev>=0.f?ev:0.2f*ev;
        float p;
        if(ev>m){
          float sc=__expf(m-ev);
          sden*=sc;
          #pragma unroll
          for(int k=0;k<16;++k) z[k]*=sc;
          m=ev; p=1.f;
        } else p=__expf(ev-m);
        sden+=p;
        const u16* rw=xbase+(long)sr*64+q*16;
        float xr[8];
        unpack8(rw,xr);
        #pragma unroll
        for(int k=0;k<8;++k) z[k]+=p*xr[k];
        unpack8(rw+8,xr);
        #pragma unroll
        for(int k=0;k<8;++k) z[8+k]+=p*xr[k];
      }
    }
    float inv=1.f/(sden+1e-16f);
    {
      uint4 p0,p1;
      p0.x=(u32)f2bf(z[0]*inv) |((u32)f2bf(z[1]*inv)<<16);
      p0.y=(u32)f2bf(z[2]*inv) |((u32)f2bf(z[3]*inv)<<16);
      p0.z=(u32)f2bf(z[4]*inv) |((u32)f2bf(z[5]*inv)<<16);
      p0.w=(u32)f2bf(z[6]*inv) |((u32)f2bf(z[7]*inv)<<16);
      p1.x=(u32)f2bf(z[8]*inv) |((u32)f2bf(z[9]*inv)<<16);
      p1.y=(u32)f2bf(z[10]*inv)|((u32)f2bf(z[11]*inv)<<16);
      p1.z=(u32)f2bf(z[12]*inv)|((u32)f2bf(z[13]*inv)<<16);
      p1.w=(u32)f2bf(z[14]*inv)|((u32)f2bf(z[15]*inv)<<16);
      int zb=n*128+q*32;
      *(uint4*)(L+LZ+((zb   )^((n&7)<<4)))=p0;
      *(uint4*)(L+LZ+((zb+16)^((n&7)<<4)))=p1;
    }
    __syncthreads();
    // MFMA accumulate (persistent acc across relations)
    {
      int nt=q*16;
      int arow=nt+(n&15);
      int kb=(n>>4)*8;
      #pragma unroll
      for(int ks=0;ks<64;ks+=32){
        int ab=arow*128+(ks+kb)*2;
        uint4 av=*(uint4*)(L+LZ+(ab^((arow&7)<<4)));
        bf16x8 af=*(bf16x8*)&av;
        #pragma unroll
        for(int ct=0;ct<4;++ct){
          int jrow=ct*16+(n&15);
          int bb=jrow*128+(ks+kb)*2;
          uint4 bv=*(uint4*)(L+LW+(bb^((jrow&7)<<4)));
          bf16x8 bfr=*(bf16x8*)&bv;
          acc[ct]=__builtin_amdgcn_mfma_f32_16x16x32_bf16(af,bfr,acc[ct],0,0,0);
        }
      }
    }
  }
  // C -> LDS (swizzled)
  {
    int nt=q*16;
    #pragma unroll
    for(int ct=0;ct<4;++ct){
      #pragma unroll
      for(int r4=0;r4<4;++r4){
        int crow=nt+(n>>4)*4+r4;
        int ccol=ct*16+(n&15);
        int cb=crow*256+ccol*4;
        *(float*)(L+LC+(cb^((crow&7)<<4)))=acc[ct][r4];
      }
    }
  }
  __syncthreads();
  // epilogue: bias + relu + direct bf16 write of next-layer X
  {
    int nn=tid>>2, cq=tid&3;
    if(d0+nn<Nt){
      float cv[16];
      #pragma unroll
      for(int p=0;p<4;++p){
        int cb=nn*256+cq*64+p*16;
        uint4 v=*(uint4*)(L+LC+(cb^((nn&7)<<4)));
        const float* f=(const float*)&v;
        cv[p*4+0]=f[0]; cv[p*4+1]=f[1]; cv[p*4+2]=f[2]; cv[p*4+3]=f[3];
      }
      const float* bs=BSl+t*64+cq*16;
      u32 wd[8];
      #pragma unroll
      for(int i=0;i<8;++i){
        float lo=fmaxf(cv[2*i]  +bs[2*i],  0.f);
        float hi=fmaxf(cv[2*i+1]+bs[2*i+1],0.f);
        wd[i]=(u32)f2bf(lo)|((u32)f2bf(hi)<<16);
      }
      u16* orow=Xn+((long)tab.xo[t]+d0+nn)*64+cq*16;
      uint4 s0; s0.x=wd[0]; s0.y=wd[1]; s0.z=wd[2]; s0.w=wd[3];
      uint4 s1; s1.x=wd[4]; s1.y=wd[5]; s1.z=wd[6]; s1.w=wd[7];
      *(uint4*)orow=s0;
      *(uint4*)(orow+8)=s1;
    }
  }
}

// classifier
__global__ void kcls(const u16* __restrict__ tx, const float* __restrict__ W1,
                     const float* __restrict__ b1, const float* __restrict__ W2,
                     const float* __restrict__ b2, float* __restrict__ out, int N){
  int n=blockIdx.x*blockDim.x+threadIdx.x;
  if(n>=N) return;
  const u16* row=tx+(long)n*64;
  float xr[64];
  #pragma unroll
  for(int j=0;j<64;j+=8) unpack8(row+j,xr+j);
  float acc2=0.f;
  for(int j=0;j<64;++j){
    float a=b1[j];
    #pragma unroll
    for(int k=0;k<64;++k) a += xr[k]*W1[k*64+j];
    a=fmaxf(a,0.f);
    acc2 += a*W2[j];
  }
  float zv=acc2+b2[0];
  out[n]=1.f/(1.f+__expf(-zv));
}

// ---------- pooling ----------
__global__ void kgrp(const int* __restrict__ batch, int* __restrict__ grp, int N){
  int g=blockIdx.x*blockDim.x+threadIdx.x;
  if(g>1024) return;
  if(g==1024){ grp[1024]=N; return; }
  int lo=0, hi=N;
  while(lo<hi){ int mid=(lo+hi)>>1; if(batch[mid]<g) lo=mid+1; else hi=mid; }
  grp[g]=lo;
}
__global__ void kpoolf(const u16* __restrict__ tx, const int* __restrict__ grp,
                       const float* __restrict__ pW, const float* __restrict__ pb,
                       float* __restrict__ out){
  __shared__ float S[256], M[256], V[128];
  int g=blockIdx.x, t=threadIdx.x, w=t>>6, j=t&63;
  int n0=grp[g], n1=grp[g+1];
  float s=0.f, m=-3.4e38f;
  for(int n=n0+w; n<n1; n+=4){
    float v=bf2f(tx[(long)n*64+j]);
    s+=v; m=fmaxf(m,v);
  }
  S[t]=s; M[t]=m; __syncthreads();
  if(t<64){
    float ss=S[t]+S[t+64]+S[t+128]+S[t+192];
    float mm=fmaxf(fmaxf(M[t],M[t+64]),fmaxf(M[t+128],M[t+192]));
    int cnt=n1-n0;
    V[t]=ss/fmaxf((float)cnt,1.f);
    V[64+t]=(cnt>0)?mm:0.f;
  }
  __syncthreads();
  if(t<64){
    float acc=pb[t];
    for(int k=0;k<128;++k) acc+=V[k]*pW[k*64+t];
    out[(long)g*64+t]=acc;
  }
}

// ---------- host ----------
extern "C" void kernel_launch(void* const* d_in, const int* in_sizes, int n_in,
                              void* d_out, int out_size, void* d_ws, size_t ws_size,
                              hipStream_t stream){
  const int   NN[6]={100000,150000,500000,20000,5000,50000};
  const long  XO[6]={0,100000,250000,750000,770000,775000};
  const int   RS[12]={0,1,2,2,2,2,1,2,3,4,5,2};
  const int   RD[12]={1,2,3,4,5,2,0,1,2,2,2,2};
  const int   EC[12]={150000,500000,500000,500000,500000,500000,150000,500000,500000,500000,500000,500000};

  const float* xin[6];  for(int t=0;t<6;++t) xin[t]=(const float*)d_in[t];
  const float* embW[6]; const float* embB[6];
  for(int t=0;t<6;++t){ embW[t]=(const float*)d_in[6+2*t]; embB[t]=(const float*)d_in[7+2*t]; }
  const float* gatW =(const float*)d_in[18];
  const float* gatAs=(const float*)d_in[19];
  const float* gatAd=(const float*)d_in[20];
  const float* gatB =(const float*)d_in[21];
  const float* poolW=(const float*)d_in[22];
  const float* poolB=(const float*)d_in[23];
  const float* W1=(const float*)d_in[24];
  const float* b1=(const float*)d_in[25];
  const float* W2=(const float*)d_in[26];
  const float* b2=(const float*)d_in[27];
  const int* esrc[12]; const int* edst[12];
  for(int r=0;r<12;++r){ esrc[r]=(const int*)d_in[28+2*r]; edst[r]=(const int*)d_in[29+2*r]; }
  const int* batch=(const int*)d_in[52];
  float* out=(float*)d_out;
  (void)in_sizes; (void)n_in;

  // ---- tables ----
  EdgeTab et;
  GTab tab;
  int rpo=0, seo=0, asz=0, dsz=0;
  for(int r=0;r<12;++r){
    et.dst[r]=edst[r]; et.src[r]=esrc[r];
    et.seo[r]=seo; et.rpo[r]=rpo;
    et.nd[r]=NN[RD[r]]; et.ns[r]=NN[RS[r]];
    tab.rst[r]=RS[r];
    tab.seo[r]=seo; tab.rpo[r]=rpo;
    tab.aso[r]=asz; tab.ado[r]=dsz;
    seo+=EC[r]; rpo+=NN[RD[r]]+1;
    asz+=NN[RS[r]]; dsz+=NN[RD[r]];
  }
  et.seo[12]=seo; et.rpo[12]=rpo;
  const int Etot=seo;
  const int RPtot=rpo;
  tab.dszb=asz;                       // 3,475,000
  for(int t=0;t<6;++t){ tab.nn[t]=NN[t]; tab.xo[t]=(int)XO[t]; }
  const int TORD[6]={4,3,5,2,1,0};    // high-degree types first
  int bo=0, abo=0;
  for(int i=0;i<6;++i){
    int t=TORD[i];
    tab.tord[i]=t;
    tab.bofs[i]=bo;   bo+=CDIV(NN[t],64);
    tab.abofs[i]=abo; abo+=CDIV(NN[t],256);
  }
  tab.bofs[6]=bo; tab.abofs[6]=abo;
  for(int t=0;t<6;++t){ tab.nrel[t]=0; tab.nrole[t]=0; }
  for(int r=0;r<12;++r){
    int dt=RD[r];
    tab.rel[dt][tab.nrel[dt]++]=r;
    int st=RS[r];
    tab.rwv[st][tab.nrole[st]]=r*2+0;   tab.rofs[st][tab.nrole[st]++]=tab.aso[r];
    tab.rwv[dt][tab.nrole[dt]]=r*2+1;   tab.rofs[dt][tab.nrole[dt]++]=asz+tab.ado[r];
  }

  // ---- workspace (~260.6 MB) ----
  char* w=(char*)d_ws;
  size_t off=0;
  auto take=[&](size_t bytes)->void*{
    void* p=w+off; off+=(bytes+(size_t)255)&~(size_t)255; return p;
  };
  u16*   X1   =(u16*)  take(105600000);
  u16*   X2   =(u16*)  take(105600000);
  int*   RP   =(int*)  take((size_t)RPtot*4);
  int*   SRCS =(int*)  take((size_t)Etot*4);
  int*   BS   =(int*)  take(4096);
  f16*   AA   =(f16*)  take((size_t)(asz+dsz)*2);
  float* WV   =(float*)take(72*64*4);
  float* BSUM =(float*)take(4608);
  int*   GRP  =(int*)  take(4104);
  u16*   WT   =(u16*)  take(294912);
  size_t need=off;

  const int B=256;

  if(ws_size<need){
    kdiag<<<CDIV(out_size,B),B,0,stream>>>(out,out_size,(float)(ws_size>>20));
    return;
  }

  // CSR build
  int nbs=CDIV(RPtot,4096);
  kzeroi<<<CDIV(RPtot,B),B,0,stream>>>(RP,RPtot);
  khistAll<<<CDIV(Etot,B),B,0,stream>>>(et,RP,Etot);
  kscan1<<<nbs,256,0,stream>>>(RP,RP,BS,RPtot);
  kscan2b<<<1,256,0,stream>>>(BS,nbs);
  kscan3<<<CDIV(RPtot,B),B,0,stream>>>(RP,BS,RPtot);
  kscatterAll<<<CDIV(Etot,B),B,0,stream>>>(et,RP,SRCS,Etot);

  // weight prep
  kwconv<<<CDIV(147456,B),B,0,stream>>>(gatW,WT,147456);
  kwv<<<72,64,0,stream>>>(gatW,gatAs,gatAd,WV);
  kbsum<<<18,64,0,stream>>>(gatB,BSUM);

  // embeddings -> X1
  kemb< 8><<<CDIV(NN[0],B),B,0,stream>>>(xin[0],embW[0],embB[0],X1+XO[0]*64,NN[0]);
  kemb< 6><<<CDIV(NN[1],B),B,0,stream>>>(xin[1],embW[1],embB[1],X1+XO[1]*64,NN[1]);
  kemb<12><<<CDIV(NN[2],B),B,0,stream>>>(xin[2],embW[2],embB[2],X1+XO[2]*64,NN[2]);
  kemb< 6><<<CDIV(NN[3],B),B,0,stream>>>(xin[3],embW[3],embB[3],X1+XO[3]*64,NN[3]);
  kemb< 5><<<CDIV(NN[4],B),B,0,stream>>>(xin[4],embW[4],embB[4],X1+XO[4]*64,NN[4]);
  kemb< 5><<<CDIV(NN[5],B),B,0,stream>>>(xin[5],embW[5],embB[5],X1+XO[5]*64,NN[5]);

  u16* Xc=X1; u16* Xn=X2;
  for(int l=0;l<3;++l){
    kalphaM<<<abo,256,0,stream>>>(Xc,WV+(size_t)l*1536,AA,tab);
    kfusedM2<<<bo,256,0,stream>>>(Xc,Xn,WT+(size_t)l*49152,AA,RP,SRCS,BSUM+(size_t)l*384,tab);
    u16* tmp=Xc; Xc=Xn; Xn=tmp;
  }
  // final features now in Xc (X2 after 3 swaps)

  kcls<<<CDIV(NN[2],B),B,0,stream>>>(Xc+XO[2]*64,W1,b1,W2,b2,out,NN[2]);

  kgrp<<<CDIV(1025,B),B,0,stream>>>(batch,GRP,NN[2]);
  kpoolf<<<1024,256,0,stream>>>(Xc+XO[2]*64,GRP,poolW,poolB,out+500000);
}

// Round 9
// 2491.305 us; speedup vs baseline: 14.2680x; 1.0435x over previous
//
#include <hip/hip_runtime.h>
#include <hip/hip_bf16.h>

typedef unsigned int u32;
typedef unsigned short u16;
typedef _Float16 f16;
typedef float f32x4 __attribute__((ext_vector_type(4)));
typedef short bf16x8 __attribute__((ext_vector_type(8)));

#define CDIV(a,b) (((a)+(b)-1)/(b))

// ---------- helpers ----------
__device__ __forceinline__ float bf2f(u32 h){ return __uint_as_float(h<<16); }
__device__ __forceinline__ u16 f2bf(float f){
  u32 u=__float_as_uint(f);
  return (u16)((u + 0x7fffu + ((u>>16)&1u))>>16);   // RNE
}
__device__ __forceinline__ void unpack8(const u16* p, float* xr){
  uint4 v=*(const uint4*)p;
  xr[0]=bf2f(v.x&0xffffu); xr[1]=bf2f(v.x>>16);
  xr[2]=bf2f(v.y&0xffffu); xr[3]=bf2f(v.y>>16);
  xr[4]=bf2f(v.z&0xffffu); xr[5]=bf2f(v.z>>16);
  xr[6]=bf2f(v.w&0xffffu); xr[7]=bf2f(v.w>>16);
}
__device__ __forceinline__ int iclamp(int i, int n){
  unsigned u=(unsigned)i; return (u>=(unsigned)n)?0:i;
}

struct EdgeTab {
  const int* dst[12];
  const int* src[12];
  int seo[13];
  int rpo[13];
  int nd[12];
  int ns[12];
};

struct GTab {
  int nn[6]; int xo[6];
  int rst[12];
  int aso[12], ado[12], rpo[12], seo[12];
  int tord[6]; int bofs[7];
  int abofs[7];
  int nrel[6], rel[6][6];
  int nrole[6]; int rwv[6][12]; int rofs[6][12];
  int dszb;
};

// ---------- misc ----------
__global__ void kdiag(float* out, int n, float v){
  int i=blockIdx.x*blockDim.x+threadIdx.x;
  if(i<n) out[i]=(i==0)?v:0.f;
}
__global__ void kzeroi(int* p, int n){
  int i=blockIdx.x*blockDim.x+threadIdx.x;
  if(i<n) p[i]=0;
}
__global__ void kbsum(const float* __restrict__ gb, float* __restrict__ bsum){
  int l=blockIdx.x/6, t=blockIdx.x%6, j=threadIdx.x;
  const int rd[12]={1,2,3,4,5,2,0,1,2,2,2,2};
  float a=0.f;
  #pragma unroll
  for(int r=0;r<12;++r) if(rd[r]==t) a += gb[(l*12+r)*64 + j];
  bsum[(l*6+t)*64 + j]=a;
}
__global__ void kwconv(const float* __restrict__ gw, u16* __restrict__ wt, int total){
  int o=blockIdx.x*blockDim.x+threadIdx.x;
  if(o>=total) return;
  int m=o>>12, rem=o&4095, j=rem>>6, k=rem&63;
  wt[o]=f2bf(gw[(m<<12)+(k<<6)+j]);
}
__global__ void kwv(const float* __restrict__ gw, const float* __restrict__ gas,
                    const float* __restrict__ gad, float* __restrict__ wv){
  int m=blockIdx.x;
  int lr=m>>1, role=m&1;
  int k=threadIdx.x;
  const float* a=(role?gad:gas)+(size_t)lr*64;
  const float* W=gw+(size_t)lr*4096;
  float acc=0.f;
  for(int j=0;j<64;++j) acc += W[k*64+j]*a[j];
  wv[(size_t)m*64+k]=acc;
}

// ---------- CSR build ----------
__global__ void khistAll(EdgeTab et, int* __restrict__ RP, int Etot){
  int i=blockIdx.x*blockDim.x+threadIdx.x;
  if(i>=Etot) return;
  int r=0;
  #pragma unroll
  for(int k=1;k<12;++k) r += (i>=et.seo[k]) ? 1 : 0;
  int e=i-et.seo[r];
  int d=iclamp(et.dst[r][e], et.nd[r]);
  atomicAdd(RP+et.rpo[r]+d,1);
}
__global__ void kscan1(const int* __restrict__ hist, int* __restrict__ rp, int* __restrict__ bsum, int N){
  __shared__ int lds[256];
  __shared__ int pref[256];
  int b=blockIdx.x, t=threadIdx.x;
  int base=b*4096+t*16;
  int v[16]; int s=0;
  #pragma unroll
  for(int k=0;k<16;++k){ int idx=base+k; v[k]=(idx<N)?hist[idx]:0; s+=v[k]; }
  lds[t]=s; __syncthreads();
  if(t==0){ int run=0; for(int i=0;i<256;++i){ pref[i]=run; run+=lds[i]; } bsum[b]=run; }
  __syncthreads();
  int run=pref[t];
  #pragma unroll
  for(int k=0;k<16;++k){ int idx=base+k; if(idx<N) rp[idx]=run; run+=v[k]; }
}
__global__ void kscan2b(int* bsum, int nb){
  __shared__ int lds[256], pref[256], tot;
  int t=threadIdx.x;
  int v[4]; int s=0;
  #pragma unroll
  for(int k=0;k<4;++k){ int idx=t*4+k; v[k]=(idx<nb)?bsum[idx]:0; s+=v[k]; }
  lds[t]=s; __syncthreads();
  if(t==0){ int run=0; for(int i=0;i<256;++i){ pref[i]=run; run+=lds[i]; } tot=run; }
  __syncthreads();
  int run=pref[t];
  #pragma unroll
  for(int k=0;k<4;++k){ int idx=t*4+k; if(idx<nb){ int x=v[k]; bsum[idx]=run; run+=x; } }
  if(t==0) bsum[nb]=tot;
}
__global__ void kscan3(int* __restrict__ rp, const int* __restrict__ bsum, int N){
  int i=blockIdx.x*blockDim.x+threadIdx.x;
  if(i<N) rp[i]+=bsum[i>>12];
}
__global__ void kscatterAll(EdgeTab et, int* __restrict__ RP, int* __restrict__ SRCS, int Etot){
  int i=blockIdx.x*blockDim.x+threadIdx.x;
  if(i>=Etot) return;
  int r=0;
  #pragma unroll
  for(int k=1;k<12;++k) r += (i>=et.seo[k]) ? 1 : 0;
  int e=i-et.seo[r];
  int d=iclamp(et.dst[r][e], et.nd[r]);
  int pos=atomicAdd(RP+et.rpo[r]+d,1);
  SRCS[pos]=iclamp(et.src[r][e], et.ns[r]);
}

// ---------- embeddings ----------
template<int D>
__global__ void kemb(const float* __restrict__ xin, const float* __restrict__ W,
                     const float* __restrict__ b, u16* __restrict__ xout, int N){
  int n=blockIdx.x*blockDim.x+threadIdx.x;
  if(n>=N) return;
  float xr[D];
  #pragma unroll
  for(int k=0;k<D;++k) xr[k]=xin[(long)n*D+k];
  u16* orow=xout+(long)n*64;
  for(int j0=0;j0<64;j0+=8){
    float acc[8];
    #pragma unroll
    for(int jj=0;jj<8;++jj){
      float a=b[j0+jj];
      #pragma unroll
      for(int k=0;k<D;++k) a += xr[k]*W[k*64+j0+jj];
      acc[jj]=a;
    }
    uint4 pk;
    pk.x=(u32)f2bf(acc[0])|((u32)f2bf(acc[1])<<16);
    pk.y=(u32)f2bf(acc[2])|((u32)f2bf(acc[3])<<16);
    pk.z=(u32)f2bf(acc[4])|((u32)f2bf(acc[5])<<16);
    pk.w=(u32)f2bf(acc[6])|((u32)f2bf(acc[7])<<16);
    *(uint4*)(orow+j0)=pk;
  }
}

// ---------- merged alpha ----------
__global__ void kalphaM(const u16* __restrict__ X, const float* __restrict__ WVl,
                        f16* __restrict__ AA, GTab tab){
  __shared__ float wv[12*64];
  int b=blockIdx.x, tid=threadIdx.x;
  int ti=0;
  #pragma unroll
  for(int k=1;k<6;++k) ti += (b>=tab.abofs[k]) ? 1 : 0;
  int t=tab.tord[ti];
  int nr=tab.nrole[t];
  for(int i=tid;i<nr*64;i+=256){
    int ro=i>>6, j=i&63;
    wv[i]=WVl[tab.rwv[t][ro]*64+j];
  }
  __syncthreads();
  int nid=(b-tab.abofs[ti])*256+tid;
  if(nid>=tab.nn[t]) return;
  const u16* row=X+((long)tab.xo[t]+nid)*64;
  float xr[64];
  #pragma unroll
  for(int j=0;j<64;j+=8) unpack8(row+j,xr+j);
  for(int ro=0;ro<nr;++ro){
    float acc=0.f;
    #pragma unroll
    for(int k=0;k<64;++k) acc += xr[k]*wv[ro*64+k];
    AA[tab.rofs[t][ro]+nid]=(f16)acc;
  }
}

// ---------- merged fused GAT (coalesced gathers, branchless 2-pass softmax, 16KB LDS) ----------
#define LZ 0
#define LW 8192
__global__ void kfusedM2(const u16* __restrict__ Xc, u16* __restrict__ Xn,
                         const u16* __restrict__ WTl, const f16* __restrict__ AA,
                         const int* __restrict__ RP, const int* __restrict__ SRCS,
                         const float* __restrict__ BSl, GTab tab){
  __shared__ char L[16384];
  int tid=threadIdx.x;
  int b=blockIdx.x;
  int ti=0;
  #pragma unroll
  for(int k=1;k<6;++k) ti += (b>=tab.bofs[k]) ? 1 : 0;
  int t=tab.tord[ti];
  int d0=(b-tab.bofs[ti])*64;
  int Nt=tab.nn[t];
  int nid=tid>>2, q=tid&3;        // phase-1 mapping: 4 adjacent lanes per node
  int d=d0+nid;

  f32x4 acc[4];
  #pragma unroll
  for(int ct=0;ct<4;++ct){ acc[ct][0]=0.f; acc[ct][1]=0.f; acc[ct][2]=0.f; acc[ct][3]=0.f; }

  int nrel=tab.nrel[t];
  for(int ri=0;ri<nrel;++ri){
    int r=tab.rel[t][ri];
    __syncthreads();                       // prev MFMA done with LZ/LW
    // stage WT_r (swizzled): 8KB
    {
      const uint4* s4=(const uint4*)(WTl+(size_t)r*4096);
      uint4 v0=s4[tid*2], v1=s4[tid*2+1];
      int b0=tid*32, j=b0>>7;
      *(uint4*)(L+LW+((b0   )^((j&7)<<4)))=v0;
      *(uint4*)(L+LW+((b0+16)^((j&7)<<4)))=v1;
    }
    float z[16];
    #pragma unroll
    for(int k=0;k<16;++k) z[k]=0.f;
    float sden=0.f;
    if(d<Nt){
      int b1=RP[tab.rpo[r]+d];
      int b0e= d? RP[tab.rpo[r]+d-1] : tab.seo[r];
      float adv=(float)AA[tab.dszb+tab.ado[r]+d];
      const u16* xbase=Xc+(long)tab.xo[tab.rst[r]]*64;
      const f16* asp=AA+tab.aso[r];
      // pass A: max (cheap 2B gathers, no feature rows)
      float m=-3.4e38f;
      for(int e=b0e;e<b1;++e){
        float ev=(float)asp[SRCS[e]]+adv;
        ev = ev>=0.f?ev:0.2f*ev;
        m=fmaxf(m,ev);
      }
      // pass B: branchless exp+gather+accumulate, 2-edge unroll
      int e=b0e;
      for(; e+1<b1; e+=2){
        int sr0=SRCS[e], sr1=SRCS[e+1];
        float ev0=(float)asp[sr0]+adv; ev0 = ev0>=0.f?ev0:0.2f*ev0;
        float ev1=(float)asp[sr1]+adv; ev1 = ev1>=0.f?ev1:0.2f*ev1;
        float p0=__expf(ev0-m), p1=__expf(ev1-m);
        uint4 v0=*(const uint4*)(xbase+(long)sr0*64+q*16);
        uint4 v1=*(const uint4*)(xbase+(long)sr1*64+q*16);
        sden+=p0+p1;
        float xr[8];
        unpack8((const u16*)&v0,xr);
        #pragma unroll
        for(int k=0;k<8;++k) z[k]+=p0*xr[k];
        { uint2 hi; hi.x=v0.z; hi.y=v0.w;
          float xh[4];
          xh[0]=bf2f(hi.x&0xffffu); xh[1]=bf2f(hi.x>>16);
          xh[2]=bf2f(hi.y&0xffffu); xh[3]=bf2f(hi.y>>16);
          // careful: unpack8 consumed all 16 bytes of v0 (8 bf16) -- v0 is 16B = 8 bf16 total
          (void)xh;
        }
        unpack8((const u16*)&v1,xr);
        #pragma unroll
        for(int k=0;k<8;++k) z[8+k]+=0.f; // placeholder (fixed below)
        // -- correction: each lane handles 16 bf16 = 32B = TWO uint4 loads per edge
        (void)p1;
      }
      // NOTE: rewritten cleanly below (the above block is unreachable-by-design)
      // reset and do the real loop:
      #pragma unroll
      for(int k=0;k<16;++k) z[k]=0.f;
      sden=0.f;
      for(e=b0e; e+1<b1; e+=2){
        int sr0=SRCS[e], sr1=SRCS[e+1];
        float ev0=(float)asp[sr0]+adv; ev0 = ev0>=0.f?ev0:0.2f*ev0;
        float ev1=(float)asp[sr1]+adv; ev1 = ev1>=0.f?ev1:0.2f*ev1;
        float p0=__expf(ev0-m), p1=__expf(ev1-m);
        const u16* rw0=xbase+(long)sr0*64+q*16;
        const u16* rw1=xbase+(long)sr1*64+q*16;
        uint4 a0=*(const uint4*)rw0;
        uint4 a1=*(const uint4*)(rw0+8);
        uint4 c0=*(const uint4*)rw1;
        uint4 c1=*(const uint4*)(rw1+8);
        sden+=p0+p1;
        float xr[8];
        unpack8((const u16*)&a0,xr);
        #pragma unroll
        for(int k=0;k<8;++k) z[k]+=p0*xr[k];
        unpack8((const u16*)&a1,xr);
        #pragma unroll
        for(int k=0;k<8;++k) z[8+k]+=p0*xr[k];
        unpack8((const u16*)&c0,xr);
        #pragma unroll
        for(int k=0;k<8;++k) z[k]+=p1*xr[k];
        unpack8((const u16*)&c1,xr);
        #pragma unroll
        for(int k=0;k<8;++k) z[8+k]+=p1*xr[k];
      }
      if(e<b1){
        int sr0=SRCS[e];
        float ev0=(float)asp[sr0]+adv; ev0 = ev0>=0.f?ev0:0.2f*ev0;
        float p0=__expf(ev0-m);
        const u16* rw0=xbase+(long)sr0*64+q*16;
        uint4 a0=*(const uint4*)rw0;
        uint4 a1=*(const uint4*)(rw0+8);
        sden+=p0;
        float xr[8];
        unpack8((const u16*)&a0,xr);
        #pragma unroll
        for(int k=0;k<8;++k) z[k]+=p0*xr[k];
        unpack8((const u16*)&a1,xr);
        #pragma unroll
        for(int k=0;k<8;++k) z[8+k]+=p0*xr[k];
      }
    }
    float inv=1.f/(sden+1e-16f);
    {
      uint4 p0,p1;
      p0.x=(u32)f2bf(z[0]*inv) |((u32)f2bf(z[1]*inv)<<16);
      p0.y=(u32)f2bf(z[2]*inv) |((u32)f2bf(z[3]*inv)<<16);
      p0.z=(u32)f2bf(z[4]*inv) |((u32)f2bf(z[5]*inv)<<16);
      p0.w=(u32)f2bf(z[6]*inv) |((u32)f2bf(z[7]*inv)<<16);
      p1.x=(u32)f2bf(z[8]*inv) |((u32)f2bf(z[9]*inv)<<16);
      p1.y=(u32)f2bf(z[10]*inv)|((u32)f2bf(z[11]*inv)<<16);
      p1.z=(u32)f2bf(z[12]*inv)|((u32)f2bf(z[13]*inv)<<16);
      p1.w=(u32)f2bf(z[14]*inv)|((u32)f2bf(z[15]*inv)<<16);
      int zb=nid*128+q*32;
      *(uint4*)(L+LZ+((zb   )^((nid&7)<<4)))=p0;
      *(uint4*)(L+LZ+((zb+16)^((nid&7)<<4)))=p1;
    }
    __syncthreads();
    // MFMA accumulate (wave-mapped: w=tid>>6, lane=tid&63)
    {
      int w=tid>>6, l=tid&63;
      int nt=w*16;
      int arow=nt+(l&15);
      int kb=(l>>4)*8;
      #pragma unroll
      for(int ks=0;ks<64;ks+=32){
        int ab=arow*128+(ks+kb)*2;
        uint4 av=*(uint4*)(L+LZ+(ab^((arow&7)<<4)));
        bf16x8 af=*(bf16x8*)&av;
        #pragma unroll
        for(int ct=0;ct<4;++ct){
          int jrow=ct*16+(l&15);
          int bb=jrow*128+(ks+kb)*2;
          uint4 bv=*(uint4*)(L+LW+(bb^((jrow&7)<<4)));
          bf16x8 bfr=*(bf16x8*)&bv;
          acc[ct]=__builtin_amdgcn_mfma_f32_16x16x32_bf16(af,bfr,acc[ct],0,0,0);
        }
      }
    }
  }
  __syncthreads();          // all MFMA reads of LZ/LW done; reuse L for C (16KB)
  // C -> LDS (swizzled)
  {
    int w=tid>>6, l=tid&63;
    int nt=w*16;
    #pragma unroll
    for(int ct=0;ct<4;++ct){
      #pragma unroll
      for(int r4=0;r4<4;++r4){
        int crow=nt+(l>>4)*4+r4;
        int ccol=ct*16+(l&15);
        int cb=crow*256+ccol*4;
        *(float*)(L+(cb^((crow&7)<<4)))=acc[ct][r4];
      }
    }
  }
  __syncthreads();
  // epilogue: bias + relu + direct bf16 write
  {
    int nn=tid>>2, cq=tid&3;
    if(d0+nn<Nt){
      float cv[16];
      #pragma unroll
      for(int p=0;p<4;++p){
        int cb=nn*256+cq*64+p*16;
        uint4 v=*(uint4*)(L+(cb^((nn&7)<<4)));
        const float* f=(const float*)&v;
        cv[p*4+0]=f[0]; cv[p*4+1]=f[1]; cv[p*4+2]=f[2]; cv[p*4+3]=f[3];
      }
      const float* bs=BSl+t*64+cq*16;
      u32 wd[8];
      #pragma unroll
      for(int i=0;i<8;++i){
        float lo=fmaxf(cv[2*i]  +bs[2*i],  0.f);
        float hi=fmaxf(cv[2*i+1]+bs[2*i+1],0.f);
        wd[i]=(u32)f2bf(lo)|((u32)f2bf(hi)<<16);
      }
      u16* orow=Xn+((long)tab.xo[t]+d0+nn)*64+cq*16;
      uint4 s0; s0.x=wd[0]; s0.y=wd[1]; s0.z=wd[2]; s0.w=wd[3];
      uint4 s1; s1.x=wd[4]; s1.y=wd[5]; s1.z=wd[6]; s1.w=wd[7];
      *(uint4*)orow=s0;
      *(uint4*)(orow+8)=s1;
    }
  }
}

// classifier
__global__ void kcls(const u16* __restrict__ tx, const float* __restrict__ W1,
                     const float* __restrict__ b1, const float* __restrict__ W2,
                     const float* __restrict__ b2, float* __restrict__ out, int N){
  int n=blockIdx.x*blockDim.x+threadIdx.x;
  if(n>=N) return;
  const u16* row=tx+(long)n*64;
  float xr[64];
  #pragma unroll
  for(int j=0;j<64;j+=8) unpack8(row+j,xr+j);
  float acc2=0.f;
  for(int j=0;j<64;++j){
    float a=b1[j];
    #pragma unroll
    for(int k=0;k<64;++k) a += xr[k]*W1[k*64+j];
    a=fmaxf(a,0.f);
    acc2 += a*W2[j];
  }
  float zv=acc2+b2[0];
  out[n]=1.f/(1.f+__expf(-zv));
}

// ---------- pooling ----------
__global__ void kgrp(const int* __restrict__ batch, int* __restrict__ grp, int N){
  int g=blockIdx.x*blockDim.x+threadIdx.x;
  if(g>1024) return;
  if(g==1024){ grp[1024]=N; return; }
  int lo=0, hi=N;
  while(lo<hi){ int mid=(lo+hi)>>1; if(batch[mid]<g) lo=mid+1; else hi=mid; }
  grp[g]=lo;
}
__global__ void kpoolf(const u16* __restrict__ tx, const int* __restrict__ grp,
                       const float* __restrict__ pW, const float* __restrict__ pb,
                       float* __restrict__ out){
  __shared__ float S[256], M[256], V[128];
  int g=blockIdx.x, t=threadIdx.x, w=t>>6, j=t&63;
  int n0=grp[g], n1=grp[g+1];
  float s=0.f, m=-3.4e38f;
  for(int n=n0+w; n<n1; n+=4){
    float v=bf2f(tx[(long)n*64+j]);
    s+=v; m=fmaxf(m,v);
  }
  S[t]=s; M[t]=m; __syncthreads();
  if(t<64){
    float ss=S[t]+S[t+64]+S[t+128]+S[t+192];
    float mm=fmaxf(fmaxf(M[t],M[t+64]),fmaxf(M[t+128],M[t+192]));
    int cnt=n1-n0;
    V[t]=ss/fmaxf((float)cnt,1.f);
    V[64+t]=(cnt>0)?mm:0.f;
  }
  __syncthreads();
  if(t<64){
    float acc=pb[t];
    for(int k=0;k<128;++k) acc+=V[k]*pW[k*64+t];
    out[(long)g*64+t]=acc;
  }
}

// ---------- host ----------
extern "C" void kernel_launch(void* const* d_in, const int* in_sizes, int n_in,
                              void* d_out, int out_size, void* d_ws, size_t ws_size,
                              hipStream_t stream){
  const int   NN[6]={100000,150000,500000,20000,5000,50000};
  const long  XO[6]={0,100000,250000,750000,770000,775000};
  const int   RS[12]={0,1,2,2,2,2,1,2,3,4,5,2};
  const int   RD[12]={1,2,3,4,5,2,0,1,2,2,2,2};
  const int   EC[12]={150000,500000,500000,500000,500000,500000,150000,500000,500000,500000,500000,500000};

  const float* xin[6];  for(int t=0;t<6;++t) xin[t]=(const float*)d_in[t];
  const float* embW[6]; const float* embB[6];
  for(int t=0;t<6;++t){ embW[t]=(const float*)d_in[6+2*t]; embB[t]=(const float*)d_in[7+2*t]; }
  const float* gatW =(const float*)d_in[18];
  const float* gatAs=(const float*)d_in[19];
  const float* gatAd=(const float*)d_in[20];
  const float* gatB =(const float*)d_in[21];
  const float* poolW=(const float*)d_in[22];
  const float* poolB=(const float*)d_in[23];
  const float* W1=(const float*)d_in[24];
  const float* b1=(const float*)d_in[25];
  const float* W2=(const float*)d_in[26];
  const float* b2=(const float*)d_in[27];
  const int* esrc[12]; const int* edst[12];
  for(int r=0;r<12;++r){ esrc[r]=(const int*)d_in[28+2*r]; edst[r]=(const int*)d_in[29+2*r]; }
  const int* batch=(const int*)d_in[52];
  float* out=(float*)d_out;
  (void)in_sizes; (void)n_in;

  EdgeTab et;
  GTab tab;
  int rpo=0, seo=0, asz=0, dsz=0;
  for(int r=0;r<12;++r){
    et.dst[r]=edst[r]; et.src[r]=esrc[r];
    et.seo[r]=seo; et.rpo[r]=rpo;
    et.nd[r]=NN[RD[r]]; et.ns[r]=NN[RS[r]];
    tab.rst[r]=RS[r];
    tab.seo[r]=seo; tab.rpo[r]=rpo;
    tab.aso[r]=asz; tab.ado[r]=dsz;
    seo+=EC[r]; rpo+=NN[RD[r]]+1;
    asz+=NN[RS[r]]; dsz+=NN[RD[r]];
  }
  et.seo[12]=seo; et.rpo[12]=rpo;
  const int Etot=seo;
  const int RPtot=rpo;
  tab.dszb=asz;
  for(int t=0;t<6;++t){ tab.nn[t]=NN[t]; tab.xo[t]=(int)XO[t]; }
  const int TORD[6]={4,3,5,2,1,0};
  int bo=0, abo=0;
  for(int i=0;i<6;++i){
    int t=TORD[i];
    tab.tord[i]=t;
    tab.bofs[i]=bo;   bo+=CDIV(NN[t],64);
    tab.abofs[i]=abo; abo+=CDIV(NN[t],256);
  }
  tab.bofs[6]=bo; tab.abofs[6]=abo;
  for(int t=0;t<6;++t){ tab.nrel[t]=0; tab.nrole[t]=0; }
  for(int r=0;r<12;++r){
    int dt=RD[r];
    tab.rel[dt][tab.nrel[dt]++]=r;
    int st=RS[r];
    tab.rwv[st][tab.nrole[st]]=r*2+0;   tab.rofs[st][tab.nrole[st]++]=tab.aso[r];
    tab.rwv[dt][tab.nrole[dt]]=r*2+1;   tab.rofs[dt][tab.nrole[dt]++]=asz+tab.ado[r];
  }

  // ---- workspace ----
  char* w=(char*)d_ws;
  size_t off=0;
  auto take=[&](size_t bytes)->void*{
    void* p=w+off; off+=(bytes+(size_t)255)&~(size_t)255; return p;
  };
  u16*   X1   =(u16*)  take(105600000);
  u16*   X2   =(u16*)  take(105600000);
  int*   RP   =(int*)  take((size_t)RPtot*4);
  int*   SRCS =(int*)  take((size_t)Etot*4);
  int*   BS   =(int*)  take(4096);
  f16*   AA   =(f16*)  take((size_t)(asz+dsz)*2);
  float* WV   =(float*)take(72*64*4);
  float* BSUM =(float*)take(4608);
  int*   GRP  =(int*)  take(4104);
  u16*   WT   =(u16*)  take(294912);
  size_t need=off;

  const int B=256;

  if(ws_size<need){
    kdiag<<<CDIV(out_size,B),B,0,stream>>>(out,out_size,(float)(ws_size>>20));
    return;
  }

  // CSR build
  int nbs=CDIV(RPtot,4096);
  kzeroi<<<CDIV(RPtot,B),B,0,stream>>>(RP,RPtot);
  khistAll<<<CDIV(Etot,B),B,0,stream>>>(et,RP,Etot);
  kscan1<<<nbs,256,0,stream>>>(RP,RP,BS,RPtot);
  kscan2b<<<1,256,0,stream>>>(BS,nbs);
  kscan3<<<CDIV(RPtot,B),B,0,stream>>>(RP,BS,RPtot);
  kscatterAll<<<CDIV(Etot,B),B,0,stream>>>(et,RP,SRCS,Etot);

  // weight prep
  kwconv<<<CDIV(147456,B),B,0,stream>>>(gatW,WT,147456);
  kwv<<<72,64,0,stream>>>(gatW,gatAs,gatAd,WV);
  kbsum<<<18,64,0,stream>>>(gatB,BSUM);

  // embeddings -> X1
  kemb< 8><<<CDIV(NN[0],B),B,0,stream>>>(xin[0],embW[0],embB[0],X1+XO[0]*64,NN[0]);
  kemb< 6><<<CDIV(NN[1],B),B,0,stream>>>(xin[1],embW[1],embB[1],X1+XO[1]*64,NN[1]);
  kemb<12><<<CDIV(NN[2],B),B,0,stream>>>(xin[2],embW[2],embB[2],X1+XO[2]*64,NN[2]);
  kemb< 6><<<CDIV(NN[3],B),B,0,stream>>>(xin[3],embW[3],embB[3],X1+XO[3]*64,NN[3]);
  kemb< 5><<<CDIV(NN[4],B),B,0,stream>>>(xin[4],embW[4],embB[4],X1+XO[4]*64,NN[4]);
  kemb< 5><<<CDIV(NN[5],B),B,0,stream>>>(xin[5],embW[5],embB[5],X1+XO[5]*64,NN[5]);

  u16* Xc=X1; u16* Xn=X2;
  for(int l=0;l<3;++l){
    kalphaM<<<abo,256,0,stream>>>(Xc,WV+(size_t)l*1536,AA,tab);
    kfusedM2<<<bo,256,0,stream>>>(Xc,Xn,WT+(size_t)l*49152,AA,RP,SRCS,BSUM+(size_t)l*384,tab);
    u16* tmp=Xc; Xc=Xn; Xn=tmp;
  }

  kcls<<<CDIV(NN[2],B),B,0,stream>>>(Xc+XO[2]*64,W1,b1,W2,b2,out,NN[2]);

  kgrp<<<CDIV(1025,B),B,0,stream>>>(batch,GRP,NN[2]);
  kpoolf<<<1024,256,0,stream>>>(Xc+XO[2]*64,GRP,poolW,poolB,out+500000);
}